// Round 6
// baseline (340.884 us; speedup 1.0000x reference)
//
#include <hip/hip_runtime.h>
#include <hip/hip_bf16.h>
#include <hip/hip_fp16.h>

#define N_NODES 50000
#define N_EDGES 1600000
#define IN_CH 256
#define NEG_SLOPE 0.2f
#define EPS_F 1e-16f
#define CNT_PAD 16      // one 64B line per counter (atomic build + agg reads)
#define CAP 128         // bucket capacity per node (Poisson(32): P(>=128) ~ 1e-37)
#define KTILE 64                 // 17.4KB xs + 32KB w1s -> 3 blocks/CU
#define XS_PITCH (KTILE + 4)

__device__ __forceinline__ float lrelu(float x) {
    return x > 0.f ? x : NEG_SLOPE * x;
}

__device__ __forceinline__ float2 h2f(unsigned int w) {
    __half2 h;
    *reinterpret_cast<unsigned int*>(&h) = w;
    return __half22float2(h);
}

__device__ __forceinline__ unsigned int f2h2(float a, float b) {
    __half2 h = __floats2half2_rn(a, b);
    return *reinterpret_cast<unsigned int*>(&h);
}

// Inline int64-vs-int32 layout detection: for int64 edge_index the high words
// (odd int positions) are all zero (values in [0, 50000)); for int32 they are
// src values, all-zero with P ~ (2e-5)^64. One L2-hot load + ballot per wave.
__device__ __forceinline__ int detect_i64(const int* __restrict__ ei) {
    const int lane = threadIdx.x & 63;
    const unsigned long long b = __ballot(ei[2 * lane + 1] != 0);
    return b == 0ull ? 1 : 0;
}

__device__ __forceinline__ int ld_src(const int* ei, int f, int e) {
    return f ? ei[2 * (size_t)e] : ei[e];
}
__device__ __forceinline__ int ld_dst(const int* ei, int f, int e) {
    return f ? ei[2 * (size_t)N_EDGES + 2 * (size_t)e]
             : ei[(size_t)N_EDGES + e];
}

// -------- Single-pass CSR build: pos = atomicAdd(cnt[d]), csr[d*128+pos] = s --------
// Slot order within a node is arbitrary (atomic race order) — sums are
// order-independent within fp32 tolerance. ~32 atomics per padded counter.
__global__ __launch_bounds__(256) void k_build(const int* __restrict__ ei,
                                               int* __restrict__ cnt,
                                               int* __restrict__ csr_src)
{
    const int f = detect_i64(ei);
    const int e = blockIdx.x * 256 + threadIdx.x;
    if (e >= N_EDGES) return;
    const int s = ld_src(ei, f, e);
    const int d = ld_dst(ei, f, e);
    const int pos = atomicAdd(&cnt[(size_t)d * CNT_PAD], 1);
    if (pos < CAP) csr_src[((size_t)d << 7) + pos] = s;
}

// ---------------- Kernel 1: h1 = x @ W1 (fp16 out) ; a_src1/a_dst1 fused ----------------
// Register-blocked 2 rows x 4 cols; KTILE=64 for 3 blocks/CU occupancy.
__global__ __launch_bounds__(256) void k1_gemm1(
    const float* __restrict__ x, const float* __restrict__ W1,
    const float* __restrict__ att_src1, const float* __restrict__ att_dst1,
    __half* __restrict__ h1, float* __restrict__ a_src1, float* __restrict__ a_dst1)
{
    __shared__ float w1s[IN_CH * 32];        // full K, [k][col]  (32 KB)
    __shared__ float xs[64 * XS_PITCH];      // K-tile of 64      (17.4 KB)
    __shared__ float attss[32], attds[32];
    const int t = threadIdx.x;
    for (int i = t; i < IN_CH * 32; i += 256) w1s[i] = W1[i];
    if (t < 32) { attss[t] = att_src1[t]; attds[t] = att_dst1[t]; }
    const int row0 = blockIdx.x * 64;
    const int colq = t & 7, c4 = colq * 4;
    const int rp = t >> 3;
    const int r0 = rp * 2, r1 = r0 + 1;
    float4 a0 = make_float4(0.f, 0.f, 0.f, 0.f);
    float4 a1 = make_float4(0.f, 0.f, 0.f, 0.f);
    for (int kb = 0; kb < IN_CH; kb += KTILE) {
        __syncthreads();
        #pragma unroll
        for (int i = 0; i < 4; ++i) {        // 64 rows x 16 float4
            const int idx = t + 256 * i;
            const int r = idx >> 4, p = idx & 15;
            const int row = row0 + r;
            float4 vv = make_float4(0.f, 0.f, 0.f, 0.f);
            if (row < N_NODES)
                vv = *(const float4*)(x + (size_t)row * IN_CH + kb + p * 4);
            *(float4*)(&xs[r * XS_PITCH + p * 4]) = vv;
        }
        __syncthreads();
        #pragma unroll 8
        for (int kt = 0; kt < KTILE; ++kt) {
            const float xv0 = xs[r0 * XS_PITCH + kt];
            const float xv1 = xs[r1 * XS_PITCH + kt];
            const float4 wv = *(const float4*)(&w1s[(kb + kt) * 32 + c4]);
            a0.x += xv0 * wv.x; a0.y += xv0 * wv.y;
            a0.z += xv0 * wv.z; a0.w += xv0 * wv.w;
            a1.x += xv1 * wv.x; a1.y += xv1 * wv.y;
            a1.z += xv1 * wv.z; a1.w += xv1 * wv.w;
        }
    }
    const int row_a = row0 + r0, row_b = row0 + r1;
    if (row_a < N_NODES) {
        uint2 p; p.x = f2h2(a0.x, a0.y); p.y = f2h2(a0.z, a0.w);
        *(uint2*)(h1 + (size_t)row_a * 32 + c4) = p;
    }
    if (row_b < N_NODES) {
        uint2 p; p.x = f2h2(a1.x, a1.y); p.y = f2h2(a1.z, a1.w);
        *(uint2*)(h1 + (size_t)row_b * 32 + c4) = p;
    }
    float sa0 = a0.x * attss[c4] + a0.y * attss[c4 + 1]
              + a0.z * attss[c4 + 2] + a0.w * attss[c4 + 3];
    float sd0 = a0.x * attds[c4] + a0.y * attds[c4 + 1]
              + a0.z * attds[c4 + 2] + a0.w * attds[c4 + 3];
    float sa1 = a1.x * attss[c4] + a1.y * attss[c4 + 1]
              + a1.z * attss[c4 + 2] + a1.w * attss[c4 + 3];
    float sd1 = a1.x * attds[c4] + a1.y * attds[c4 + 1]
              + a1.z * attds[c4 + 2] + a1.w * attds[c4 + 3];
    sa0 += __shfl_xor(sa0, 1); sa0 += __shfl_xor(sa0, 2);
    sd0 += __shfl_xor(sd0, 1); sd0 += __shfl_xor(sd0, 2);
    sa1 += __shfl_xor(sa1, 1); sa1 += __shfl_xor(sa1, 2);
    sd1 += __shfl_xor(sd1, 1); sd1 += __shfl_xor(sd1, 2);
    const int head = colq >> 2;
    if ((colq & 3) == 0) {
        if (row_a < N_NODES) {
            a_src1[row_a * 2 + head] = sa0;
            a_dst1[row_a * 2 + head] = sd0;
        }
        if (row_b < N_NODES) {
            a_src1[row_b * 2 + head] = sa1;
            a_dst1[row_b * 2 + head] = sd1;
        }
    }
}

// -------- Layer-1 aggregation FUSED with layer-2 transform --------
// Edge loop: half2-packed gathers, 4 edge-slots/wave (round-2 form — the
// lane-cooperative variant regressed: bpermute cost > expf dedup gain).
// Epilogue: the wave holds all 32 channels of out1 for its node -> apply
// bias+ELU, 32->16 GEMV with W2, and a_src2/a_dst2 dots in-register/LDS.
__global__ __launch_bounds__(256) void k_agg1f(
    const int* __restrict__ cnt, const int* __restrict__ csr_src,
    const float* __restrict__ a_src1, const float* __restrict__ a_dst1,
    const __half* __restrict__ h1,
    const float* __restrict__ b1, const float* __restrict__ W2,
    const float* __restrict__ att_src2, const float* __restrict__ att_dst2,
    __half* __restrict__ h2, float* __restrict__ a_src2, float* __restrict__ a_dst2)
{
    __shared__ float w2s[32 * 16];
    __shared__ float b1s[32], as2[16], ad2[16];
    __shared__ float act_s[4][32];
    const int t = threadIdx.x;
    for (int i = t; i < 512; i += 256) w2s[i] = W2[i];
    if (t < 32) b1s[t] = b1[t];
    if (t < 16) { as2[t] = att_src2[t]; ad2[t] = att_dst2[t]; }

    const int wid = (blockIdx.x * 256 + t) >> 6;       // grid is exactly 50000 waves
    const int lane = t & 63;
    const int wv = t >> 6;
    const int active = (wid < N_NODES);
    const int len = active ? min(cnt[(size_t)wid * CNT_PAD], CAP) : 0;
    const int beg = wid << 7, end = beg + len;
    float2 ad = make_float2(0.f, 0.f);
    if (active) ad = *(const float2*)(a_dst1 + 2 * (size_t)wid);
    const int slot = lane >> 4, chp = lane & 15;
    const int head = chp >> 3;
    const float adh = head ? ad.y : ad.x;
    const int rep = ((chp & 7) == 0);
    const unsigned int* __restrict__ h1u = (const unsigned int*)h1;
    float accx = 0.f, accy = 0.f, sw = 0.f;
    int i = beg + slot;
    for (; i + 28 < end; i += 32) {          // 32 edges / wave-iter
        int s[8]; float a[8]; unsigned int hw[8]; float w[8];
        #pragma unroll
        for (int j = 0; j < 8; ++j) s[j] = csr_src[i + 4 * j];
        #pragma unroll
        for (int j = 0; j < 8; ++j) a[j] = a_src1[2 * (size_t)s[j] + head];
        #pragma unroll
        for (int j = 0; j < 8; ++j) hw[j] = h1u[(size_t)s[j] * 16 + chp];
        #pragma unroll
        for (int j = 0; j < 8; ++j) w[j] = __expf(lrelu(a[j] + adh));
        float wsum = 0.f;
        #pragma unroll
        for (int j = 0; j < 8; ++j) {
            const float2 hf = h2f(hw[j]);
            wsum += w[j];
            accx += w[j] * hf.x; accy += w[j] * hf.y;
        }
        if (rep) sw += wsum;
    }
    for (; i + 12 < end; i += 16) {          // mid tier: 16 edges / wave-iter
        int s[4]; float a[4]; unsigned int hw[4]; float w[4];
        #pragma unroll
        for (int j = 0; j < 4; ++j) s[j] = csr_src[i + 4 * j];
        #pragma unroll
        for (int j = 0; j < 4; ++j) a[j] = a_src1[2 * (size_t)s[j] + head];
        #pragma unroll
        for (int j = 0; j < 4; ++j) hw[j] = h1u[(size_t)s[j] * 16 + chp];
        #pragma unroll
        for (int j = 0; j < 4; ++j) w[j] = __expf(lrelu(a[j] + adh));
        float wsum = 0.f;
        #pragma unroll
        for (int j = 0; j < 4; ++j) {
            const float2 hf = h2f(hw[j]);
            wsum += w[j];
            accx += w[j] * hf.x; accy += w[j] * hf.y;
        }
        if (rep) sw += wsum;
    }
    for (; i < end; i += 4) {
        const int s = csr_src[i];
        const float w = __expf(lrelu(a_src1[2 * (size_t)s + head] + adh));
        if (rep) sw += w;
        const float2 hf = h2f(h1u[(size_t)s * 16 + chp]);
        accx += w * hf.x; accy += w * hf.y;
    }
    // reduce across the 4 slots (lanes differ in bits 4,5)
    sw += __shfl_xor(sw, 16); sw += __shfl_xor(sw, 32);
    const float swh = __shfl(sw, head << 3);
    accx += __shfl_xor(accx, 16); accx += __shfl_xor(accx, 32);
    accy += __shfl_xor(accy, 16); accy += __shfl_xor(accy, 32);
    const float inv = 1.f / (swh + EPS_F);
    // ---- fused layer-2 transform (was k4_layer2) ----
    if (lane < 16) {
        float ax = accx * inv + b1s[2 * chp];
        float ay = accy * inv + b1s[2 * chp + 1];
        ax = ax > 0.f ? ax : expm1f(ax);
        ay = ay > 0.f ? ay : expm1f(ay);
        act_s[wv][2 * chp] = ax;
        act_s[wv][2 * chp + 1] = ay;
    }
    __syncthreads();            // covers w2s/b1s/as2/ad2 loads + act_s writes
    const int j = lane & 15;
    float acc2 = 0.f;
    #pragma unroll
    for (int k = 0; k < 32; ++k) acc2 += act_s[wv][k] * w2s[k * 16 + j];
    if (lane < 16 && active) h2[(size_t)wid * 16 + j] = __float2half(acc2);
    float sa = acc2 * as2[j], sd = acc2 * ad2[j];
    sa += __shfl_xor(sa, 1); sa += __shfl_xor(sa, 2);
    sa += __shfl_xor(sa, 4); sa += __shfl_xor(sa, 8);
    sd += __shfl_xor(sd, 1); sd += __shfl_xor(sd, 2);
    sd += __shfl_xor(sd, 4); sd += __shfl_xor(sd, 8);
    if (lane == 0 && active) { a_src2[wid] = sa; a_dst2[wid] = sd; }
}

// -------- Layer-2 aggregation FUSED with edge-MLP node hoist --------
// Edge loop: half2-packed h2 gathers, 8 edge-slots/wave (round-2 form).
// Epilogue: wave holds all 16 channels of out2 -> compute u/v = (out2+b2)@Wm1
// halves directly.
__global__ __launch_bounds__(256) void k_agg2f(
    const int* __restrict__ cnt, const int* __restrict__ csr_src,
    const float* __restrict__ a_src2, const float* __restrict__ a_dst2,
    const __half* __restrict__ h2,
    const float* __restrict__ b2, const float* __restrict__ Wm1,
    const float* __restrict__ bm1,
    __half* __restrict__ u, __half* __restrict__ v)
{
    __shared__ float wa[16 * 16], wb[16 * 16];
    __shared__ float b2s[16], bm1s[16];
    __shared__ float act_s[4][16];
    const int t = threadIdx.x;
    if (t < 256) { wa[t] = Wm1[t]; wb[t] = Wm1[256 + t]; }
    if (t < 16) { b2s[t] = b2[t]; bm1s[t] = bm1[t]; }

    const int wid = (blockIdx.x * 256 + t) >> 6;
    const int lane = t & 63;
    const int wv = t >> 6;
    const int active = (wid < N_NODES);
    const int len = active ? min(cnt[(size_t)wid * CNT_PAD], CAP) : 0;
    const int beg = wid << 7, end = beg + len;
    const float ad = active ? a_dst2[wid] : 0.f;
    const int slot = lane >> 3, chp = lane & 7;
    const int rep = (chp == 0);
    const unsigned int* __restrict__ h2u = (const unsigned int*)h2;
    float accx = 0.f, accy = 0.f, sw = 0.f;
    int i = beg + slot;
    for (; i + 24 < end; i += 32) {          // 32 edges / wave-iter
        int s[4]; float a[4]; unsigned int hw[4]; float w[4];
        #pragma unroll
        for (int j = 0; j < 4; ++j) s[j] = csr_src[i + 8 * j];
        #pragma unroll
        for (int j = 0; j < 4; ++j) a[j] = a_src2[s[j]];
        #pragma unroll
        for (int j = 0; j < 4; ++j) hw[j] = h2u[(size_t)s[j] * 8 + chp];
        #pragma unroll
        for (int j = 0; j < 4; ++j) w[j] = __expf(lrelu(a[j] + ad));
        float wsum = 0.f;
        #pragma unroll
        for (int j = 0; j < 4; ++j) {
            const float2 hf = h2f(hw[j]);
            wsum += w[j];
            accx += w[j] * hf.x; accy += w[j] * hf.y;
        }
        if (rep) sw += wsum;
    }
    for (; i < end; i += 8) {
        const int s = csr_src[i];
        const float w = __expf(lrelu(a_src2[s] + ad));
        if (rep) sw += w;
        const float2 hf = h2f(h2u[(size_t)s * 8 + chp]);
        accx += w * hf.x; accy += w * hf.y;
    }
    // reduce across the 8 slots (lanes differ in bits 3,4,5)
    sw += __shfl_xor(sw, 8); sw += __shfl_xor(sw, 16); sw += __shfl_xor(sw, 32);
    const float swt = __shfl(sw, 0);
    accx += __shfl_xor(accx, 8); accx += __shfl_xor(accx, 16); accx += __shfl_xor(accx, 32);
    accy += __shfl_xor(accy, 8); accy += __shfl_xor(accy, 16); accy += __shfl_xor(accy, 32);
    const float inv = 1.f / (swt + EPS_F);
    // ---- fused edge-MLP node hoist (was k_prep) ----
    if (lane < 8) {
        float2 o;
        o.x = accx * inv + b2s[2 * chp];
        o.y = accy * inv + b2s[2 * chp + 1];
        *(float2*)(&act_s[wv][2 * chp]) = o;
    }
    __syncthreads();            // covers wa/wb/b2s/bm1s loads + act_s writes
    const int c = lane & 15;
    float su = bm1s[c], sv = 0.f;
    #pragma unroll
    for (int k = 0; k < 16; ++k) {
        const float a = act_s[wv][k];
        su += a * wa[k * 16 + c];
        sv += a * wb[k * 16 + c];
    }
    if (lane < 16 && active) {
        u[(size_t)wid * 16 + c] = __float2half(su);
        v[(size_t)wid * 16 + c] = __float2half(sv);
    }
}

// ---------------- Kernel 7 lite: per-edge tail of the MLP (fp16 gathers) ----------------
__global__ __launch_bounds__(256) void k7_lite(
    const int* __restrict__ ei,
    const __half* __restrict__ u, const __half* __restrict__ v,
    const float* __restrict__ Wm2, const float* __restrict__ bm2,
    float* __restrict__ out)
{
    __shared__ float wm2s[16];
    __shared__ float bm2s;
    const int t = threadIdx.x;
    const int f = detect_i64(ei);
    if (t < 16) wm2s[t] = Wm2[t];
    if (t == 0) bm2s = bm2[0];
    __syncthreads();
    const int e = blockIdx.x * 256 + t;
    if (e >= N_EDGES) return;
    const int s = ld_src(ei, f, e);
    const int d = ld_dst(ei, f, e);
    const uint4* up = (const uint4*)(u + (size_t)s * 16);
    const uint4* vp = (const uint4*)(v + (size_t)d * 16);
    const uint4 ua = up[0], ub = up[1];
    const uint4 va = vp[0], vb = vp[1];
    float fl = bm2s;
    unsigned int uw[8] = {ua.x, ua.y, ua.z, ua.w, ub.x, ub.y, ub.z, ub.w};
    unsigned int vw[8] = {va.x, va.y, va.z, va.w, vb.x, vb.y, vb.z, vb.w};
    #pragma unroll
    for (int i = 0; i < 8; ++i) {
        const float2 a = h2f(uw[i]);
        const float2 b = h2f(vw[i]);
        fl += fmaxf(a.x + b.x, 0.f) * wm2s[2 * i];
        fl += fmaxf(a.y + b.y, 0.f) * wm2s[2 * i + 1];
    }
    out[e] = fmaxf(fl, 0.f);
}

extern "C" void kernel_launch(void* const* d_in, const int* in_sizes, int n_in,
                              void* d_out, int out_size, void* d_ws, size_t ws_size,
                              hipStream_t stream)
{
    const float* x        = (const float*)d_in[0];
    const int*   ei       = (const int*)d_in[1];
    const float* W1       = (const float*)d_in[2];
    const float* att_src1 = (const float*)d_in[3];
    const float* att_dst1 = (const float*)d_in[4];
    const float* b1       = (const float*)d_in[5];
    const float* W2       = (const float*)d_in[6];
    const float* att_src2 = (const float*)d_in[7];
    const float* att_dst2 = (const float*)d_in[8];
    const float* b2       = (const float*)d_in[9];
    const float* Wm1      = (const float*)d_in[10];
    const float* bm1      = (const float*)d_in[11];
    const float* Wm2      = (const float*)d_in[12];
    const float* bm2      = (const float*)d_in[13];

    float* ws = (float*)d_ws;
    size_t off = 0;
    __half* h1 = (__half*)(ws + off); off += 16 * (size_t)N_NODES;
    float* a_src1 = ws + off; off += 2  * (size_t)N_NODES;
    float* a_dst1 = ws + off; off += 2  * (size_t)N_NODES;
    float* spare1 = ws + off; off += 32 * (size_t)N_NODES;
    __half* h2 = (__half*)(ws + off); off += 16 * (size_t)N_NODES;
    float* a_src2 = ws + off; off += 1  * (size_t)N_NODES;
    float* a_dst2 = ws + off; off += 1  * (size_t)N_NODES;
    float* spare2 = ws + off; off += 16 * (size_t)N_NODES;
    __half* u = (__half*)(ws + off); off += 8 * (size_t)N_NODES;
    __half* v = (__half*)(ws + off); off += 8 * (size_t)N_NODES;
    int* cnt     = (int*)(ws + off); off += (size_t)N_NODES * CNT_PAD;
    int* csr_src = (int*)(ws + off); off += (size_t)N_NODES * CAP;
    (void)spare1; (void)spare2;

    // zero the atomic counters (3.2 MB; ~0.5 us at fill BW)
    hipMemsetAsync(cnt, 0, (size_t)N_NODES * CNT_PAD * sizeof(int), stream);
    k_build<<<(N_EDGES + 255) / 256, 256, 0, stream>>>(ei, cnt, csr_src);

    k1_gemm1<<<(N_NODES + 63) / 64, 256, 0, stream>>>(
        x, W1, att_src1, att_dst1, h1, a_src1, a_dst1);
    k_agg1f<<<(N_NODES + 3) / 4, 256, 0, stream>>>(
        cnt, csr_src, a_src1, a_dst1, h1, b1, W2, att_src2, att_dst2,
        h2, a_src2, a_dst2);
    k_agg2f<<<(N_NODES + 3) / 4, 256, 0, stream>>>(
        cnt, csr_src, a_src2, a_dst2, h2, b2, Wm1, bm1, u, v);
    k7_lite<<<(N_EDGES + 255) / 256, 256, 0, stream>>>(
        ei, u, v, Wm2, bm2, (float*)d_out);
}

// Round 7
// 281.820 us; speedup vs baseline: 1.2096x; 1.2096x over previous
//
#include <hip/hip_runtime.h>
#include <hip/hip_bf16.h>
#include <hip/hip_fp16.h>

#define N_NODES 50000
#define N_EDGES 1600000
#define IN_CH 256
#define NEG_SLOPE 0.2f
#define EPS_F 1e-16f
#define CNT_PAD 16      // one 64B line per counter (agg kernels read cnt[n*16])
#define CAP 128         // bucket capacity per node (Poisson(32): P(>=128) ~ 1e-37)
#define NBK 196         // coarse buckets: dst>>8, 50000/256 -> 0..195
#define CAPB 10240      // coarse bucket capacity (mean 8163, +23 sigma)
#define PCHUNK 3125     // edges per k_part block (1024 threads x <=4 edges)
#define KTILE 64                 // 17.4KB xs + 32KB w1s -> 3 blocks/CU
#define XS_PITCH (KTILE + 4)

__device__ __forceinline__ float lrelu(float x) {
    return x > 0.f ? x : NEG_SLOPE * x;
}

__device__ __forceinline__ float2 h2f(unsigned int w) {
    __half2 h;
    *reinterpret_cast<unsigned int*>(&h) = w;
    return __half22float2(h);
}

__device__ __forceinline__ unsigned int f2h2(float a, float b) {
    __half2 h = __floats2half2_rn(a, b);
    return *reinterpret_cast<unsigned int*>(&h);
}

// Inline int64-vs-int32 layout detection: for int64 edge_index the high words
// (odd int positions) are all zero (values in [0, 50000)); for int32 they are
// src values, all-zero with P ~ (2e-5)^64. One L2-hot load + ballot per wave.
__device__ __forceinline__ int detect_i64(const int* __restrict__ ei) {
    const int lane = threadIdx.x & 63;
    const unsigned long long b = __ballot(ei[2 * lane + 1] != 0);
    return b == 0ull ? 1 : 0;
}

__device__ __forceinline__ int ld_src(const int* ei, int f, int e) {
    return f ? ei[2 * (size_t)e] : ei[e];
}
__device__ __forceinline__ int ld_dst(const int* ei, int f, int e) {
    return f ? ei[2 * (size_t)N_EDGES + 2 * (size_t)e]
             : ei[(size_t)N_EDGES + e];
}

// -------- Build pass 1: coarse partition by dst>>8, edges register-cached --------
__global__ __launch_bounds__(1024) void k_part(const int* __restrict__ ei,
                                               int* __restrict__ gcnt,
                                               int2* __restrict__ bseg)
{
    __shared__ int hist[NBK];
    __shared__ int cur[NBK];
    const int t = threadIdx.x;
    const int f = detect_i64(ei);
    for (int j = t; j < NBK; j += 1024) hist[j] = 0;
    __syncthreads();
    const int e0 = blockIdx.x * PCHUNK;
    const int e1 = min(e0 + PCHUNK, N_EDGES);
    int es[4], ed[4];
    int ne = 0;
    #pragma unroll
    for (int q = 0; q < 4; ++q) {
        const int e = e0 + t + 1024 * q;
        if (e < e1) {
            es[ne] = ld_src(ei, f, e);
            ed[ne] = ld_dst(ei, f, e);
            ++ne;
        }
    }
    for (int q = 0; q < ne; ++q) atomicAdd(&hist[ed[q] >> 8], 1);
    __syncthreads();
    for (int j = t; j < NBK; j += 1024)
        cur[j] = j * CAPB + atomicAdd(&gcnt[j], hist[j]);
    __syncthreads();
    for (int q = 0; q < ne; ++q) {
        const int bk = ed[q] >> 8;
        const int pos = atomicAdd(&cur[bk], 1);
        if (pos - bk * CAPB < CAPB) bseg[pos] = make_int2(es[q], ed[q]);
    }
}

// -------- Build pass 2: per-bucket fine scatter into fixed-stride CSR records --------
// Runs AFTER k1_gemm1 so per-edge layer-1 softmax weights (fp32, identical
// math to the old agg loop) are precomputed here ONCE per edge instead of
// redundantly in 16 lanes of k_agg1f. Record: {src, w_head0, w_head1, pad}.
// Writes stay inside this block's 256-node csr window (~2 MB) — no the
// round-6 write-amplification pathology.
__global__ __launch_bounds__(1024) void k_sub(const int* __restrict__ gcnt,
                                              const int2* __restrict__ bseg,
                                              const float* __restrict__ a_src1,
                                              const float* __restrict__ a_dst1,
                                              int* __restrict__ cnt,
                                              int4* __restrict__ csr_rec)
{
    __shared__ int cur[256];
    const int b = blockIdx.x;
    const int t = threadIdx.x;
    if (t < 256) cur[t] = 0;
    __syncthreads();
    const int count = min(gcnt[b], CAPB);
    const int2* seg = bseg + (size_t)b * CAPB;
    for (int i = t; i < count; i += 1024) {
        const int2 e = seg[i];
        const int slot = atomicAdd(&cur[e.y & 255], 1);
        if (slot < CAP) {
            const float2 as = *(const float2*)(a_src1 + 2 * (size_t)e.x);
            const float2 ad = *(const float2*)(a_dst1 + 2 * (size_t)e.y);
            const float w0 = __expf(lrelu(as.x + ad.x));
            const float w1 = __expf(lrelu(as.y + ad.y));
            int4 r;
            r.x = e.x;
            r.y = __float_as_int(w0);
            r.z = __float_as_int(w1);
            r.w = 0;
            csr_rec[((size_t)e.y << 7) + slot] = r;
        }
    }
    __syncthreads();
    if (t < 256) {
        const int n = b * 256 + t;
        if (n < N_NODES) cnt[(size_t)n * CNT_PAD] = min(cur[t], CAP);
    }
}

// ---------------- Kernel 1: h1 = x @ W1 (fp16 out) ; a_src1/a_dst1 fused ----------------
// Register-blocked 2 rows x 4 cols; KTILE=64 for 3 blocks/CU occupancy.
__global__ __launch_bounds__(256) void k1_gemm1(
    const float* __restrict__ x, const float* __restrict__ W1,
    const float* __restrict__ att_src1, const float* __restrict__ att_dst1,
    __half* __restrict__ h1, float* __restrict__ a_src1, float* __restrict__ a_dst1)
{
    __shared__ float w1s[IN_CH * 32];        // full K, [k][col]  (32 KB)
    __shared__ float xs[64 * XS_PITCH];      // K-tile of 64      (17.4 KB)
    __shared__ float attss[32], attds[32];
    const int t = threadIdx.x;
    for (int i = t; i < IN_CH * 32; i += 256) w1s[i] = W1[i];
    if (t < 32) { attss[t] = att_src1[t]; attds[t] = att_dst1[t]; }
    const int row0 = blockIdx.x * 64;
    const int colq = t & 7, c4 = colq * 4;
    const int rp = t >> 3;
    const int r0 = rp * 2, r1 = r0 + 1;
    float4 a0 = make_float4(0.f, 0.f, 0.f, 0.f);
    float4 a1 = make_float4(0.f, 0.f, 0.f, 0.f);
    for (int kb = 0; kb < IN_CH; kb += KTILE) {
        __syncthreads();
        #pragma unroll
        for (int i = 0; i < 4; ++i) {        // 64 rows x 16 float4
            const int idx = t + 256 * i;
            const int r = idx >> 4, p = idx & 15;
            const int row = row0 + r;
            float4 vv = make_float4(0.f, 0.f, 0.f, 0.f);
            if (row < N_NODES)
                vv = *(const float4*)(x + (size_t)row * IN_CH + kb + p * 4);
            *(float4*)(&xs[r * XS_PITCH + p * 4]) = vv;
        }
        __syncthreads();
        #pragma unroll 8
        for (int kt = 0; kt < KTILE; ++kt) {
            const float xv0 = xs[r0 * XS_PITCH + kt];
            const float xv1 = xs[r1 * XS_PITCH + kt];
            const float4 wv = *(const float4*)(&w1s[(kb + kt) * 32 + c4]);
            a0.x += xv0 * wv.x; a0.y += xv0 * wv.y;
            a0.z += xv0 * wv.z; a0.w += xv0 * wv.w;
            a1.x += xv1 * wv.x; a1.y += xv1 * wv.y;
            a1.z += xv1 * wv.z; a1.w += xv1 * wv.w;
        }
    }
    const int row_a = row0 + r0, row_b = row0 + r1;
    if (row_a < N_NODES) {
        uint2 p; p.x = f2h2(a0.x, a0.y); p.y = f2h2(a0.z, a0.w);
        *(uint2*)(h1 + (size_t)row_a * 32 + c4) = p;
    }
    if (row_b < N_NODES) {
        uint2 p; p.x = f2h2(a1.x, a1.y); p.y = f2h2(a1.z, a1.w);
        *(uint2*)(h1 + (size_t)row_b * 32 + c4) = p;
    }
    float sa0 = a0.x * attss[c4] + a0.y * attss[c4 + 1]
              + a0.z * attss[c4 + 2] + a0.w * attss[c4 + 3];
    float sd0 = a0.x * attds[c4] + a0.y * attds[c4 + 1]
              + a0.z * attds[c4 + 2] + a0.w * attds[c4 + 3];
    float sa1 = a1.x * attss[c4] + a1.y * attss[c4 + 1]
              + a1.z * attss[c4 + 2] + a1.w * attss[c4 + 3];
    float sd1 = a1.x * attds[c4] + a1.y * attds[c4 + 1]
              + a1.z * attds[c4 + 2] + a1.w * attds[c4 + 3];
    sa0 += __shfl_xor(sa0, 1); sa0 += __shfl_xor(sa0, 2);
    sd0 += __shfl_xor(sd0, 1); sd0 += __shfl_xor(sd0, 2);
    sa1 += __shfl_xor(sa1, 1); sa1 += __shfl_xor(sa1, 2);
    sd1 += __shfl_xor(sd1, 1); sd1 += __shfl_xor(sd1, 2);
    const int head = colq >> 2;
    if ((colq & 3) == 0) {
        if (row_a < N_NODES) {
            a_src1[row_a * 2 + head] = sa0;
            a_dst1[row_a * 2 + head] = sd0;
        }
        if (row_b < N_NODES) {
            a_src1[row_b * 2 + head] = sa1;
            a_dst1[row_b * 2 + head] = sd1;
        }
    }
}

// -------- Layer-1 aggregation FUSED with layer-2 transform --------
// Edge loop consumes precomputed {s, w0, w1} records: no logit gather, no
// expf — one int4 load + one h1 half2 load per edge-slot per lane.
// Epilogue: bias+ELU, 32->16 GEMV with W2, a_src2/a_dst2 dots (was k4_layer2).
__global__ __launch_bounds__(256) void k_agg1f(
    const int* __restrict__ cnt, const int4* __restrict__ csr_rec,
    const float* __restrict__ a_dst1,   // unused (kept for signature stability)
    const __half* __restrict__ h1,
    const float* __restrict__ b1, const float* __restrict__ W2,
    const float* __restrict__ att_src2, const float* __restrict__ att_dst2,
    __half* __restrict__ h2, float* __restrict__ a_src2, float* __restrict__ a_dst2)
{
    __shared__ float w2s[32 * 16];
    __shared__ float b1s[32], as2[16], ad2[16];
    __shared__ float act_s[4][32];
    const int t = threadIdx.x;
    for (int i = t; i < 512; i += 256) w2s[i] = W2[i];
    if (t < 32) b1s[t] = b1[t];
    if (t < 16) { as2[t] = att_src2[t]; ad2[t] = att_dst2[t]; }

    const int wid = (blockIdx.x * 256 + t) >> 6;       // grid is exactly 50000 waves
    const int lane = t & 63;
    const int wv = t >> 6;
    const int active = (wid < N_NODES);
    const int len = active ? min(cnt[(size_t)wid * CNT_PAD], CAP) : 0;
    const int beg = wid << 7, end = beg + len;
    const int slot = lane >> 4, chp = lane & 15;
    const int head = chp >> 3;
    const int rep = ((chp & 7) == 0);
    const unsigned int* __restrict__ h1u = (const unsigned int*)h1;
    float accx = 0.f, accy = 0.f, sw = 0.f;
    int i = beg + slot;
    for (; i + 28 < end; i += 32) {          // 32 edges / wave-iter
        int4 r[8]; unsigned int hw[8];
        #pragma unroll
        for (int j = 0; j < 8; ++j) r[j] = csr_rec[i + 4 * j];
        #pragma unroll
        for (int j = 0; j < 8; ++j) hw[j] = h1u[(size_t)r[j].x * 16 + chp];
        float wsum = 0.f;
        #pragma unroll
        for (int j = 0; j < 8; ++j) {
            const float w = __int_as_float(head ? r[j].z : r[j].y);
            const float2 hf = h2f(hw[j]);
            wsum += w;
            accx += w * hf.x; accy += w * hf.y;
        }
        if (rep) sw += wsum;
    }
    for (; i + 12 < end; i += 16) {          // mid tier: 16 edges / wave-iter
        int4 r[4]; unsigned int hw[4];
        #pragma unroll
        for (int j = 0; j < 4; ++j) r[j] = csr_rec[i + 4 * j];
        #pragma unroll
        for (int j = 0; j < 4; ++j) hw[j] = h1u[(size_t)r[j].x * 16 + chp];
        float wsum = 0.f;
        #pragma unroll
        for (int j = 0; j < 4; ++j) {
            const float w = __int_as_float(head ? r[j].z : r[j].y);
            const float2 hf = h2f(hw[j]);
            wsum += w;
            accx += w * hf.x; accy += w * hf.y;
        }
        if (rep) sw += wsum;
    }
    for (; i < end; i += 4) {
        const int4 r = csr_rec[i];
        const float w = __int_as_float(head ? r.z : r.y);
        if (rep) sw += w;
        const float2 hf = h2f(h1u[(size_t)r.x * 16 + chp]);
        accx += w * hf.x; accy += w * hf.y;
    }
    // reduce across the 4 slots (lanes differ in bits 4,5)
    sw += __shfl_xor(sw, 16); sw += __shfl_xor(sw, 32);
    const float swh = __shfl(sw, head << 3);
    accx += __shfl_xor(accx, 16); accx += __shfl_xor(accx, 32);
    accy += __shfl_xor(accy, 16); accy += __shfl_xor(accy, 32);
    const float inv = 1.f / (swh + EPS_F);
    // ---- fused layer-2 transform (was k4_layer2) ----
    if (lane < 16) {
        float ax = accx * inv + b1s[2 * chp];
        float ay = accy * inv + b1s[2 * chp + 1];
        ax = ax > 0.f ? ax : expm1f(ax);
        ay = ay > 0.f ? ay : expm1f(ay);
        act_s[wv][2 * chp] = ax;
        act_s[wv][2 * chp + 1] = ay;
    }
    __syncthreads();            // covers w2s/b1s/as2/ad2 loads + act_s writes
    const int j = lane & 15;
    float acc2 = 0.f;
    #pragma unroll
    for (int k = 0; k < 32; ++k) acc2 += act_s[wv][k] * w2s[k * 16 + j];
    if (lane < 16 && active) h2[(size_t)wid * 16 + j] = __float2half(acc2);
    float sa = acc2 * as2[j], sd = acc2 * ad2[j];
    sa += __shfl_xor(sa, 1); sa += __shfl_xor(sa, 2);
    sa += __shfl_xor(sa, 4); sa += __shfl_xor(sa, 8);
    sd += __shfl_xor(sd, 1); sd += __shfl_xor(sd, 2);
    sd += __shfl_xor(sd, 4); sd += __shfl_xor(sd, 8);
    if (lane == 0 && active) { a_src2[wid] = sa; a_dst2[wid] = sd; }
}

// -------- Layer-2 aggregation FUSED with edge-MLP node hoist --------
// Edge loop: half2-packed h2 gathers, 8 edge-slots/wave (round-2 form);
// src index read from csr_rec.x (stride 16B).
// Epilogue: wave holds all 16 channels of out2 -> compute u/v = (out2+b2)@Wm1
// halves directly.
__global__ __launch_bounds__(256) void k_agg2f(
    const int* __restrict__ cnt, const int4* __restrict__ csr_rec,
    const float* __restrict__ a_src2, const float* __restrict__ a_dst2,
    const __half* __restrict__ h2,
    const float* __restrict__ b2, const float* __restrict__ Wm1,
    const float* __restrict__ bm1,
    __half* __restrict__ u, __half* __restrict__ v)
{
    __shared__ float wa[16 * 16], wb[16 * 16];
    __shared__ float b2s[16], bm1s[16];
    __shared__ float act_s[4][16];
    const int t = threadIdx.x;
    if (t < 256) { wa[t] = Wm1[t]; wb[t] = Wm1[256 + t]; }
    if (t < 16) { b2s[t] = b2[t]; bm1s[t] = bm1[t]; }

    const int wid = (blockIdx.x * 256 + t) >> 6;
    const int lane = t & 63;
    const int wv = t >> 6;
    const int active = (wid < N_NODES);
    const int len = active ? min(cnt[(size_t)wid * CNT_PAD], CAP) : 0;
    const int beg = wid << 7, end = beg + len;
    const float ad = active ? a_dst2[wid] : 0.f;
    const int slot = lane >> 3, chp = lane & 7;
    const int rep = (chp == 0);
    const unsigned int* __restrict__ h2u = (const unsigned int*)h2;
    float accx = 0.f, accy = 0.f, sw = 0.f;
    int i = beg + slot;
    for (; i + 24 < end; i += 32) {          // 32 edges / wave-iter
        int s[4]; float a[4]; unsigned int hw[4]; float w[4];
        #pragma unroll
        for (int j = 0; j < 4; ++j) s[j] = csr_rec[i + 8 * j].x;
        #pragma unroll
        for (int j = 0; j < 4; ++j) a[j] = a_src2[s[j]];
        #pragma unroll
        for (int j = 0; j < 4; ++j) hw[j] = h2u[(size_t)s[j] * 8 + chp];
        #pragma unroll
        for (int j = 0; j < 4; ++j) w[j] = __expf(lrelu(a[j] + ad));
        float wsum = 0.f;
        #pragma unroll
        for (int j = 0; j < 4; ++j) {
            const float2 hf = h2f(hw[j]);
            wsum += w[j];
            accx += w[j] * hf.x; accy += w[j] * hf.y;
        }
        if (rep) sw += wsum;
    }
    for (; i < end; i += 8) {
        const int s = csr_rec[i].x;
        const float w = __expf(lrelu(a_src2[s] + ad));
        if (rep) sw += w;
        const float2 hf = h2f(h2u[(size_t)s * 8 + chp]);
        accx += w * hf.x; accy += w * hf.y;
    }
    // reduce across the 8 slots (lanes differ in bits 3,4,5)
    sw += __shfl_xor(sw, 8); sw += __shfl_xor(sw, 16); sw += __shfl_xor(sw, 32);
    const float swt = __shfl(sw, 0);
    accx += __shfl_xor(accx, 8); accx += __shfl_xor(accx, 16); accx += __shfl_xor(accx, 32);
    accy += __shfl_xor(accy, 8); accy += __shfl_xor(accy, 16); accy += __shfl_xor(accy, 32);
    const float inv = 1.f / (swt + EPS_F);
    // ---- fused edge-MLP node hoist (was k_prep) ----
    if (lane < 8) {
        float2 o;
        o.x = accx * inv + b2s[2 * chp];
        o.y = accy * inv + b2s[2 * chp + 1];
        *(float2*)(&act_s[wv][2 * chp]) = o;
    }
    __syncthreads();            // covers wa/wb/b2s/bm1s loads + act_s writes
    const int c = lane & 15;
    float su = bm1s[c], sv = 0.f;
    #pragma unroll
    for (int k = 0; k < 16; ++k) {
        const float a = act_s[wv][k];
        su += a * wa[k * 16 + c];
        sv += a * wb[k * 16 + c];
    }
    if (lane < 16 && active) {
        u[(size_t)wid * 16 + c] = __float2half(su);
        v[(size_t)wid * 16 + c] = __float2half(sv);
    }
}

// ---------------- Kernel 7 lite: per-edge tail of the MLP (fp16 gathers) ----------------
__global__ __launch_bounds__(256) void k7_lite(
    const int* __restrict__ ei,
    const __half* __restrict__ u, const __half* __restrict__ v,
    const float* __restrict__ Wm2, const float* __restrict__ bm2,
    float* __restrict__ out)
{
    __shared__ float wm2s[16];
    __shared__ float bm2s;
    const int t = threadIdx.x;
    const int f = detect_i64(ei);
    if (t < 16) wm2s[t] = Wm2[t];
    if (t == 0) bm2s = bm2[0];
    __syncthreads();
    const int e = blockIdx.x * 256 + t;
    if (e >= N_EDGES) return;
    const int s = ld_src(ei, f, e);
    const int d = ld_dst(ei, f, e);
    const uint4* up = (const uint4*)(u + (size_t)s * 16);
    const uint4* vp = (const uint4*)(v + (size_t)d * 16);
    const uint4 ua = up[0], ub = up[1];
    const uint4 va = vp[0], vb = vp[1];
    float fl = bm2s;
    unsigned int uw[8] = {ua.x, ua.y, ua.z, ua.w, ub.x, ub.y, ub.z, ub.w};
    unsigned int vw[8] = {va.x, va.y, va.z, va.w, vb.x, vb.y, vb.z, vb.w};
    #pragma unroll
    for (int i = 0; i < 8; ++i) {
        const float2 a = h2f(uw[i]);
        const float2 b = h2f(vw[i]);
        fl += fmaxf(a.x + b.x, 0.f) * wm2s[2 * i];
        fl += fmaxf(a.y + b.y, 0.f) * wm2s[2 * i + 1];
    }
    out[e] = fmaxf(fl, 0.f);
}

extern "C" void kernel_launch(void* const* d_in, const int* in_sizes, int n_in,
                              void* d_out, int out_size, void* d_ws, size_t ws_size,
                              hipStream_t stream)
{
    const float* x        = (const float*)d_in[0];
    const int*   ei       = (const int*)d_in[1];
    const float* W1       = (const float*)d_in[2];
    const float* att_src1 = (const float*)d_in[3];
    const float* att_dst1 = (const float*)d_in[4];
    const float* b1       = (const float*)d_in[5];
    const float* W2       = (const float*)d_in[6];
    const float* att_src2 = (const float*)d_in[7];
    const float* att_dst2 = (const float*)d_in[8];
    const float* b2       = (const float*)d_in[9];
    const float* Wm1      = (const float*)d_in[10];
    const float* bm1      = (const float*)d_in[11];
    const float* Wm2      = (const float*)d_in[12];
    const float* bm2      = (const float*)d_in[13];

    float* ws = (float*)d_ws;
    size_t off = 0;
    __half* h1 = (__half*)(ws + off); off += 16 * (size_t)N_NODES;
    float* a_src1 = ws + off; off += 2  * (size_t)N_NODES;
    float* a_dst1 = ws + off; off += 2  * (size_t)N_NODES;
    __half* h2 = (__half*)(ws + off); off += 8 * (size_t)N_NODES;
    float* a_src2 = ws + off; off += 1  * (size_t)N_NODES;
    float* a_dst2 = ws + off; off += 1  * (size_t)N_NODES;
    __half* u = (__half*)(ws + off); off += 8 * (size_t)N_NODES;
    __half* v = (__half*)(ws + off); off += 8 * (size_t)N_NODES;
    int* cnt      = (int*)(ws + off);  off += (size_t)N_NODES * CNT_PAD;
    int4* csr_rec = (int4*)(ws + off); off += (size_t)N_NODES * CAP * 4;
    int2* bseg    = (int2*)(ws + off); off += (size_t)NBK * CAPB * 2;
    int* gcnt     = (int*)(ws + off);  off += 256;
    // total ~131 MB; workspace is >=256 MB (harness poison fills 262144 KB)

    hipMemsetAsync(gcnt, 0, 256 * sizeof(int), stream);
    k1_gemm1<<<(N_NODES + 63) / 64, 256, 0, stream>>>(
        x, W1, att_src1, att_dst1, h1, a_src1, a_dst1);
    k_part<<<(N_EDGES + PCHUNK - 1) / PCHUNK, 1024, 0, stream>>>(ei, gcnt, bseg);
    k_sub<<<NBK, 1024, 0, stream>>>(gcnt, bseg, a_src1, a_dst1, cnt, csr_rec);

    k_agg1f<<<(N_NODES + 3) / 4, 256, 0, stream>>>(
        cnt, csr_rec, a_dst1, h1, b1, W2, att_src2, att_dst2,
        h2, a_src2, a_dst2);
    k_agg2f<<<(N_NODES + 3) / 4, 256, 0, stream>>>(
        cnt, csr_rec, a_src2, a_dst2, h2, b2, Wm1, bm1, u, v);
    k7_lite<<<(N_EDGES + 255) / 256, 256, 0, stream>>>(
        ei, u, v, Wm2, bm2, (float*)d_out);
}

// Round 9
// 251.611 us; speedup vs baseline: 1.3548x; 1.1201x over previous
//
#include <hip/hip_runtime.h>
#include <hip/hip_bf16.h>
#include <hip/hip_fp16.h>

#define N_NODES 50000
#define N_EDGES 1600000
#define IN_CH 256
#define NEG_SLOPE 0.2f
#define EPS_F 1e-16f
#define CNT_PAD 16      // one 64B line per counter (agg kernels read cnt[n*16])
#define CAP 128         // bucket capacity per node (Poisson(32): P(>=128) ~ 1e-37)
#define NBK 196         // coarse buckets: dst>>8, 50000/256 -> 0..195
#define CAPB 10240      // coarse bucket capacity (mean 8163, +23 sigma)
#define PCHUNK 3125     // edges per k_part block (1024 threads x <=4 edges)
#define KTILE 64                 // 17.4KB xs + 32KB w1s -> 3 blocks/CU
#define XS_PITCH (KTILE + 4)

__device__ __forceinline__ float lrelu(float x) {
    return x > 0.f ? x : NEG_SLOPE * x;
}

__device__ __forceinline__ float2 h2f(unsigned int w) {
    __half2 h;
    *reinterpret_cast<unsigned int*>(&h) = w;
    return __half22float2(h);
}

__device__ __forceinline__ unsigned int f2h2(float a, float b) {
    __half2 h = __floats2half2_rn(a, b);
    return *reinterpret_cast<unsigned int*>(&h);
}

// Inline int64-vs-int32 layout detection: for int64 edge_index the high words
// (odd int positions) are all zero (values in [0, 50000)); for int32 they are
// src values, all-zero with P ~ (2e-5)^64. One L2-hot load + ballot per wave.
__device__ __forceinline__ int detect_i64(const int* __restrict__ ei) {
    const int lane = threadIdx.x & 63;
    const unsigned long long b = __ballot(ei[2 * lane + 1] != 0);
    return b == 0ull ? 1 : 0;
}

__device__ __forceinline__ int ld_src(const int* ei, int f, int e) {
    return f ? ei[2 * (size_t)e] : ei[e];
}
__device__ __forceinline__ int ld_dst(const int* ei, int f, int e) {
    return f ? ei[2 * (size_t)N_EDGES + 2 * (size_t)e]
             : ei[(size_t)N_EDGES + e];
}

// -------- Build pass 1: coarse partition by dst>>8, edges register-cached --------
__global__ __launch_bounds__(1024) void k_part(const int* __restrict__ ei,
                                               int* __restrict__ gcnt,
                                               int2* __restrict__ bseg)
{
    __shared__ int hist[NBK];
    __shared__ int cur[NBK];
    const int t = threadIdx.x;
    const int f = detect_i64(ei);
    for (int j = t; j < NBK; j += 1024) hist[j] = 0;
    __syncthreads();
    const int e0 = blockIdx.x * PCHUNK;
    const int e1 = min(e0 + PCHUNK, N_EDGES);
    int es[4], ed[4];
    int ne = 0;
    #pragma unroll
    for (int q = 0; q < 4; ++q) {
        const int e = e0 + t + 1024 * q;
        if (e < e1) {
            es[ne] = ld_src(ei, f, e);
            ed[ne] = ld_dst(ei, f, e);
            ++ne;
        }
    }
    for (int q = 0; q < ne; ++q) atomicAdd(&hist[ed[q] >> 8], 1);
    __syncthreads();
    for (int j = t; j < NBK; j += 1024)
        cur[j] = j * CAPB + atomicAdd(&gcnt[j], hist[j]);
    __syncthreads();
    for (int q = 0; q < ne; ++q) {
        const int bk = ed[q] >> 8;
        const int pos = atomicAdd(&cur[bk], 1);
        if (pos - bk * CAPB < CAPB) bseg[pos] = make_int2(es[q], ed[q]);
    }
}

// -------- Build pass 2: per-bucket fine scatter into fixed-stride CSR --------
// Round-2 form (plain int src records — the int4 weight-record variant
// regressed: record stream 4x, k_sub +19us, agg1f unchanged).
__global__ __launch_bounds__(1024) void k_sub(const int* __restrict__ gcnt,
                                              const int2* __restrict__ bseg,
                                              int* __restrict__ cnt,
                                              int* __restrict__ csr_src)
{
    __shared__ int cur[256];
    const int b = blockIdx.x;
    const int t = threadIdx.x;
    if (t < 256) cur[t] = 0;
    __syncthreads();
    const int count = min(gcnt[b], CAPB);
    const int2* seg = bseg + (size_t)b * CAPB;
    for (int i = t; i < count; i += 1024) {
        const int2 e = seg[i];
        const int slot = atomicAdd(&cur[e.y & 255], 1);
        if (slot < CAP) csr_src[((size_t)e.y << 7) + slot] = e.x;
    }
    __syncthreads();
    if (t < 256) {
        const int n = b * 256 + t;
        if (n < N_NODES) cnt[(size_t)n * CNT_PAD] = min(cur[t], CAP);
    }
}

// ---------------- Kernel 1: h1 = x @ W1 (fp16 out) ; a_src1/a_dst1 fused ----------------
// Register-blocked 2 rows x 4 cols; KTILE=64 for 3 blocks/CU occupancy.
__global__ __launch_bounds__(256) void k1_gemm1(
    const float* __restrict__ x, const float* __restrict__ W1,
    const float* __restrict__ att_src1, const float* __restrict__ att_dst1,
    __half* __restrict__ h1, float* __restrict__ a_src1, float* __restrict__ a_dst1)
{
    __shared__ float w1s[IN_CH * 32];        // full K, [k][col]  (32 KB)
    __shared__ float xs[64 * XS_PITCH];      // K-tile of 64      (17.4 KB)
    __shared__ float attss[32], attds[32];
    const int t = threadIdx.x;
    for (int i = t; i < IN_CH * 32; i += 256) w1s[i] = W1[i];
    if (t < 32) { attss[t] = att_src1[t]; attds[t] = att_dst1[t]; }
    const int row0 = blockIdx.x * 64;
    const int colq = t & 7, c4 = colq * 4;
    const int rp = t >> 3;
    const int r0 = rp * 2, r1 = r0 + 1;
    float4 a0 = make_float4(0.f, 0.f, 0.f, 0.f);
    float4 a1 = make_float4(0.f, 0.f, 0.f, 0.f);
    for (int kb = 0; kb < IN_CH; kb += KTILE) {
        __syncthreads();
        #pragma unroll
        for (int i = 0; i < 4; ++i) {        // 64 rows x 16 float4
            const int idx = t + 256 * i;
            const int r = idx >> 4, p = idx & 15;
            const int row = row0 + r;
            float4 vv = make_float4(0.f, 0.f, 0.f, 0.f);
            if (row < N_NODES)
                vv = *(const float4*)(x + (size_t)row * IN_CH + kb + p * 4);
            *(float4*)(&xs[r * XS_PITCH + p * 4]) = vv;
        }
        __syncthreads();
        #pragma unroll 8
        for (int kt = 0; kt < KTILE; ++kt) {
            const float xv0 = xs[r0 * XS_PITCH + kt];
            const float xv1 = xs[r1 * XS_PITCH + kt];
            const float4 wv = *(const float4*)(&w1s[(kb + kt) * 32 + c4]);
            a0.x += xv0 * wv.x; a0.y += xv0 * wv.y;
            a0.z += xv0 * wv.z; a0.w += xv0 * wv.w;
            a1.x += xv1 * wv.x; a1.y += xv1 * wv.y;
            a1.z += xv1 * wv.z; a1.w += xv1 * wv.w;
        }
    }
    const int row_a = row0 + r0, row_b = row0 + r1;
    if (row_a < N_NODES) {
        uint2 p; p.x = f2h2(a0.x, a0.y); p.y = f2h2(a0.z, a0.w);
        *(uint2*)(h1 + (size_t)row_a * 32 + c4) = p;
    }
    if (row_b < N_NODES) {
        uint2 p; p.x = f2h2(a1.x, a1.y); p.y = f2h2(a1.z, a1.w);
        *(uint2*)(h1 + (size_t)row_b * 32 + c4) = p;
    }
    float sa0 = a0.x * attss[c4] + a0.y * attss[c4 + 1]
              + a0.z * attss[c4 + 2] + a0.w * attss[c4 + 3];
    float sd0 = a0.x * attds[c4] + a0.y * attds[c4 + 1]
              + a0.z * attds[c4 + 2] + a0.w * attds[c4 + 3];
    float sa1 = a1.x * attss[c4] + a1.y * attss[c4 + 1]
              + a1.z * attss[c4 + 2] + a1.w * attss[c4 + 3];
    float sd1 = a1.x * attds[c4] + a1.y * attds[c4 + 1]
              + a1.z * attds[c4 + 2] + a1.w * attds[c4 + 3];
    sa0 += __shfl_xor(sa0, 1); sa0 += __shfl_xor(sa0, 2);
    sd0 += __shfl_xor(sd0, 1); sd0 += __shfl_xor(sd0, 2);
    sa1 += __shfl_xor(sa1, 1); sa1 += __shfl_xor(sa1, 2);
    sd1 += __shfl_xor(sd1, 1); sd1 += __shfl_xor(sd1, 2);
    const int head = colq >> 2;
    if ((colq & 3) == 0) {
        if (row_a < N_NODES) {
            a_src1[row_a * 2 + head] = sa0;
            a_dst1[row_a * 2 + head] = sd0;
        }
        if (row_b < N_NODES) {
            a_src1[row_b * 2 + head] = sa1;
            a_dst1[row_b * 2 + head] = sd1;
        }
    }
}

// -------- Layer-1 aggregation: 4 NODES PER WAVE (latency-MLP restructure) --------
// lane = 16*group + chp; each 16-lane group walks ALL of its node's edges
// 8-deep predicated. Same wave-level instruction count as the 4-slot form,
// but 4 independent load chains per wave, and NO cross-slot reductions:
// every lane holds the full weight sum for its (node, head) locally.
// Epilogue (fused ex-k4_layer2): bias+ELU, 32->16 GEMV, a_src2/a_dst2 dots.
__global__ __launch_bounds__(256) void k_agg1f(
    const int* __restrict__ cnt, const int* __restrict__ csr_src,
    const float* __restrict__ a_src1, const float* __restrict__ a_dst1,
    const __half* __restrict__ h1,
    const float* __restrict__ b1, const float* __restrict__ W2,
    const float* __restrict__ att_src2, const float* __restrict__ att_dst2,
    __half* __restrict__ h2, float* __restrict__ a_src2, float* __restrict__ a_dst2)
{
    __shared__ float w2s[32 * 16];
    __shared__ float b1s[32], as2[16], ad2[16];
    __shared__ float act_s[16][33];          // 16 nodes/block; +1 pad vs bank conflict
    const int t = threadIdx.x;
    for (int i = t; i < 512; i += 256) w2s[i] = W2[i];
    if (t < 32) b1s[t] = b1[t];
    if (t < 16) { as2[t] = att_src2[t]; ad2[t] = att_dst2[t]; }

    const int lane = t & 63;
    const int wv = t >> 6;
    const int g = lane >> 4;                 // node group within wave
    const int chp = lane & 15;               // channel pair
    const int head = chp >> 3;
    const int node = blockIdx.x * 16 + wv * 4 + g;   // grid 3125*16 = 50000 exact
    const int active = (node < N_NODES);
    const int len = active ? min(cnt[(size_t)node * CNT_PAD], CAP) : 0;
    const int beg = node << 7;
    const float adh = active ? a_dst1[2 * (size_t)node + head] : 0.f;
    const unsigned int* __restrict__ h1u = (const unsigned int*)h1;
    float accx = 0.f, accy = 0.f, sw = 0.f;
    for (int bi = 0; __any(bi < len); bi += 8) {
        int s[8]; float a[8]; unsigned int hw[8]; float w[8];
        #pragma unroll
        for (int j = 0; j < 8; ++j) {
            // idx <= beg+127: always inside this node's own 128-slot bucket.
            int sv = csr_src[beg + bi + j];
            s[j] = (bi + j < len) ? sv : 0;  // clamp garbage before address use
        }
        #pragma unroll
        for (int j = 0; j < 8; ++j) a[j] = a_src1[2 * (size_t)s[j] + head];
        #pragma unroll
        for (int j = 0; j < 8; ++j) hw[j] = h1u[(size_t)s[j] * 16 + chp];
        #pragma unroll
        for (int j = 0; j < 8; ++j)
            w[j] = (bi + j < len) ? __expf(lrelu(a[j] + adh)) : 0.f;
        #pragma unroll
        for (int j = 0; j < 8; ++j) {
            const float2 hf = h2f(hw[j]);
            sw += w[j];
            accx += w[j] * hf.x; accy += w[j] * hf.y;
        }
    }
    const float inv = 1.f / (sw + EPS_F);    // full sum held locally — no shfl
    // ---- fused layer-2 transform (was k4_layer2) ----
    const int nl = wv * 4 + g;
    {
        float ax = accx * inv + b1s[2 * chp];
        float ay = accy * inv + b1s[2 * chp + 1];
        ax = ax > 0.f ? ax : expm1f(ax);
        ay = ay > 0.f ? ay : expm1f(ay);
        act_s[nl][2 * chp] = ax;
        act_s[nl][2 * chp + 1] = ay;
    }
    __syncthreads();            // covers w2s/b1s/as2/ad2 loads + act_s writes
    const int nn = t >> 4;                   // node-local 0..15
    const int j2 = t & 15;
    const int node2 = blockIdx.x * 16 + nn;
    float acc2 = 0.f;
    #pragma unroll
    for (int k = 0; k < 32; ++k) acc2 += act_s[nn][k] * w2s[k * 16 + j2];
    if (node2 < N_NODES) h2[(size_t)node2 * 16 + j2] = __float2half(acc2);
    float sa = acc2 * as2[j2], sd = acc2 * ad2[j2];
    sa += __shfl_xor(sa, 1); sa += __shfl_xor(sa, 2);
    sa += __shfl_xor(sa, 4); sa += __shfl_xor(sa, 8);
    sd += __shfl_xor(sd, 1); sd += __shfl_xor(sd, 2);
    sd += __shfl_xor(sd, 4); sd += __shfl_xor(sd, 8);
    if (j2 == 0 && node2 < N_NODES) { a_src2[node2] = sa; a_dst2[node2] = sd; }
}

// -------- Layer-2 aggregation FUSED with edge-MLP node hoist (round-2 form) --------
__global__ __launch_bounds__(256) void k_agg2f(
    const int* __restrict__ cnt, const int* __restrict__ csr_src,
    const float* __restrict__ a_src2, const float* __restrict__ a_dst2,
    const __half* __restrict__ h2,
    const float* __restrict__ b2, const float* __restrict__ Wm1,
    const float* __restrict__ bm1,
    __half* __restrict__ u, __half* __restrict__ v)
{
    __shared__ float wa[16 * 16], wb[16 * 16];
    __shared__ float b2s[16], bm1s[16];
    __shared__ float act_s[4][16];
    const int t = threadIdx.x;
    if (t < 256) { wa[t] = Wm1[t]; wb[t] = Wm1[256 + t]; }
    if (t < 16) { b2s[t] = b2[t]; bm1s[t] = bm1[t]; }

    const int wid = (blockIdx.x * 256 + t) >> 6;
    const int lane = t & 63;
    const int wv = t >> 6;
    const int active = (wid < N_NODES);
    const int len = active ? min(cnt[(size_t)wid * CNT_PAD], CAP) : 0;
    const int beg = wid << 7, end = beg + len;
    const float ad = active ? a_dst2[wid] : 0.f;
    const int slot = lane >> 3, chp = lane & 7;
    const int rep = (chp == 0);
    const unsigned int* __restrict__ h2u = (const unsigned int*)h2;
    float accx = 0.f, accy = 0.f, sw = 0.f;
    int i = beg + slot;
    for (; i + 24 < end; i += 32) {          // 32 edges / wave-iter
        int s[4]; float a[4]; unsigned int hw[4]; float w[4];
        #pragma unroll
        for (int j = 0; j < 4; ++j) s[j] = csr_src[i + 8 * j];
        #pragma unroll
        for (int j = 0; j < 4; ++j) a[j] = a_src2[s[j]];
        #pragma unroll
        for (int j = 0; j < 4; ++j) hw[j] = h2u[(size_t)s[j] * 8 + chp];
        #pragma unroll
        for (int j = 0; j < 4; ++j) w[j] = __expf(lrelu(a[j] + ad));
        float wsum = 0.f;
        #pragma unroll
        for (int j = 0; j < 4; ++j) {
            const float2 hf = h2f(hw[j]);
            wsum += w[j];
            accx += w[j] * hf.x; accy += w[j] * hf.y;
        }
        if (rep) sw += wsum;
    }
    for (; i < end; i += 8) {
        const int s = csr_src[i];
        const float w = __expf(lrelu(a_src2[s] + ad));
        if (rep) sw += w;
        const float2 hf = h2f(h2u[(size_t)s * 8 + chp]);
        accx += w * hf.x; accy += w * hf.y;
    }
    // reduce across the 8 slots (lanes differ in bits 3,4,5)
    sw += __shfl_xor(sw, 8); sw += __shfl_xor(sw, 16); sw += __shfl_xor(sw, 32);
    const float swt = __shfl(sw, 0);
    accx += __shfl_xor(accx, 8); accx += __shfl_xor(accx, 16); accx += __shfl_xor(accx, 32);
    accy += __shfl_xor(accy, 8); accy += __shfl_xor(accy, 16); accy += __shfl_xor(accy, 32);
    const float inv = 1.f / (swt + EPS_F);
    // ---- fused edge-MLP node hoist (was k_prep) ----
    if (lane < 8) {
        float2 o;
        o.x = accx * inv + b2s[2 * chp];
        o.y = accy * inv + b2s[2 * chp + 1];
        *(float2*)(&act_s[wv][2 * chp]) = o;
    }
    __syncthreads();            // covers wa/wb/b2s/bm1s loads + act_s writes
    const int c = lane & 15;
    float su = bm1s[c], sv = 0.f;
    #pragma unroll
    for (int k = 0; k < 16; ++k) {
        const float a = act_s[wv][k];
        su += a * wa[k * 16 + c];
        sv += a * wb[k * 16 + c];
    }
    if (lane < 16 && active) {
        u[(size_t)wid * 16 + c] = __float2half(su);
        v[(size_t)wid * 16 + c] = __float2half(sv);
    }
}

// ---------------- Kernel 7 lite: per-edge tail of the MLP (fp16 gathers) ----------------
__global__ __launch_bounds__(256) void k7_lite(
    const int* __restrict__ ei,
    const __half* __restrict__ u, const __half* __restrict__ v,
    const float* __restrict__ Wm2, const float* __restrict__ bm2,
    float* __restrict__ out)
{
    __shared__ float wm2s[16];
    __shared__ float bm2s;
    const int t = threadIdx.x;
    const int f = detect_i64(ei);
    if (t < 16) wm2s[t] = Wm2[t];
    if (t == 0) bm2s = bm2[0];
    __syncthreads();
    const int e = blockIdx.x * 256 + t;
    if (e >= N_EDGES) return;
    const int s = ld_src(ei, f, e);
    const int d = ld_dst(ei, f, e);
    const uint4* up = (const uint4*)(u + (size_t)s * 16);
    const uint4* vp = (const uint4*)(v + (size_t)d * 16);
    const uint4 ua = up[0], ub = up[1];
    const uint4 va = vp[0], vb = vp[1];
    float fl = bm2s;
    unsigned int uw[8] = {ua.x, ua.y, ua.z, ua.w, ub.x, ub.y, ub.z, ub.w};
    unsigned int vw[8] = {va.x, va.y, va.z, va.w, vb.x, vb.y, vb.z, vb.w};
    #pragma unroll
    for (int i = 0; i < 8; ++i) {
        const float2 a = h2f(uw[i]);
        const float2 b = h2f(vw[i]);
        fl += fmaxf(a.x + b.x, 0.f) * wm2s[2 * i];
        fl += fmaxf(a.y + b.y, 0.f) * wm2s[2 * i + 1];
    }
    out[e] = fmaxf(fl, 0.f);
}

extern "C" void kernel_launch(void* const* d_in, const int* in_sizes, int n_in,
                              void* d_out, int out_size, void* d_ws, size_t ws_size,
                              hipStream_t stream)
{
    const float* x        = (const float*)d_in[0];
    const int*   ei       = (const int*)d_in[1];
    const float* W1       = (const float*)d_in[2];
    const float* att_src1 = (const float*)d_in[3];
    const float* att_dst1 = (const float*)d_in[4];
    const float* b1       = (const float*)d_in[5];
    const float* W2       = (const float*)d_in[6];
    const float* att_src2 = (const float*)d_in[7];
    const float* att_dst2 = (const float*)d_in[8];
    const float* b2       = (const float*)d_in[9];
    const float* Wm1      = (const float*)d_in[10];
    const float* bm1      = (const float*)d_in[11];
    const float* Wm2      = (const float*)d_in[12];
    const float* bm2      = (const float*)d_in[13];

    float* ws = (float*)d_ws;
    size_t off = 0;
    __half* h1 = (__half*)(ws + off); off += 16 * (size_t)N_NODES;
    float* a_src1 = ws + off; off += 2  * (size_t)N_NODES;
    float* a_dst1 = ws + off; off += 2  * (size_t)N_NODES;
    __half* h2 = (__half*)(ws + off); off += 8 * (size_t)N_NODES;
    float* a_src2 = ws + off; off += 1  * (size_t)N_NODES;
    float* a_dst2 = ws + off; off += 1  * (size_t)N_NODES;
    __half* u = (__half*)(ws + off); off += 8 * (size_t)N_NODES;
    __half* v = (__half*)(ws + off); off += 8 * (size_t)N_NODES;
    int* cnt     = (int*)(ws + off);  off += (size_t)N_NODES * CNT_PAD;
    int* csr_src = (int*)(ws + off);  off += (size_t)N_NODES * CAP;
    int2* bseg   = (int2*)(ws + off); off += (size_t)NBK * CAPB * 2;
    int* gcnt    = (int*)(ws + off);  off += 256;
    // total ~54 MB; workspace >= 256 MB — all regions dedicated, no overlays.

    hipMemsetAsync(gcnt, 0, 256 * sizeof(int), stream);
    k_part<<<(N_EDGES + PCHUNK - 1) / PCHUNK, 1024, 0, stream>>>(ei, gcnt, bseg);
    k_sub<<<NBK, 1024, 0, stream>>>(gcnt, bseg, cnt, csr_src);

    k1_gemm1<<<(N_NODES + 63) / 64, 256, 0, stream>>>(
        x, W1, att_src1, att_dst1, h1, a_src1, a_dst1);
    k_agg1f<<<(N_NODES + 15) / 16, 256, 0, stream>>>(
        cnt, csr_src, a_src1, a_dst1, h1, b1, W2, att_src2, att_dst2,
        h2, a_src2, a_dst2);
    k_agg2f<<<(N_NODES + 3) / 4, 256, 0, stream>>>(
        cnt, csr_src, a_src2, a_dst2, h2, b2, Wm1, bm1, u, v);
    k7_lite<<<(N_EDGES + 255) / 256, 256, 0, stream>>>(
        ei, u, v, Wm2, bm2, (float*)d_out);
}

// Round 10
// 246.473 us; speedup vs baseline: 1.3830x; 1.0208x over previous
//
#include <hip/hip_runtime.h>
#include <hip/hip_bf16.h>
#include <hip/hip_fp16.h>

#define N_NODES 50000
#define N_EDGES 1600000
#define IN_CH 256
#define NEG_SLOPE 0.2f
#define EPS_F 1e-16f
#define CNT_PAD 16      // one 64B line per counter (agg kernels read cnt[n*16])
#define CAP 128         // bucket capacity per node (Poisson(32): P(>=128) ~ 1e-37)
#define NBK 196         // coarse buckets: dst>>8, 50000/256 -> 0..195
#define CAPB 10240      // coarse bucket capacity (mean 8163, +23 sigma)
#define PCHUNK 3125     // edges per k_part block (1024 threads x <=4 edges)
#define KTILE 64                 // 17.4KB xs + 32KB w1s -> 3 blocks/CU
#define XS_PITCH (KTILE + 4)

__device__ __forceinline__ float lrelu(float x) {
    return x > 0.f ? x : NEG_SLOPE * x;
}

__device__ __forceinline__ float2 h2f(unsigned int w) {
    __half2 h;
    *reinterpret_cast<unsigned int*>(&h) = w;
    return __half22float2(h);
}

__device__ __forceinline__ unsigned int f2h2(float a, float b) {
    __half2 h = __floats2half2_rn(a, b);
    return *reinterpret_cast<unsigned int*>(&h);
}

// Inline int64-vs-int32 layout detection: for int64 edge_index the high words
// (odd int positions) are all zero (values in [0, 50000)); for int32 they are
// src values, all-zero with P ~ (2e-5)^64. One L2-hot load + ballot per wave.
__device__ __forceinline__ int detect_i64(const int* __restrict__ ei) {
    const int lane = threadIdx.x & 63;
    const unsigned long long b = __ballot(ei[2 * lane + 1] != 0);
    return b == 0ull ? 1 : 0;
}

__device__ __forceinline__ int ld_src(const int* ei, int f, int e) {
    return f ? ei[2 * (size_t)e] : ei[e];
}
__device__ __forceinline__ int ld_dst(const int* ei, int f, int e) {
    return f ? ei[2 * (size_t)N_EDGES + 2 * (size_t)e]
             : ei[(size_t)N_EDGES + e];
}

// -------- Build pass 1: coarse partition by dst>>8, edges register-cached --------
__global__ __launch_bounds__(1024) void k_part(const int* __restrict__ ei,
                                               int* __restrict__ gcnt,
                                               int2* __restrict__ bseg)
{
    __shared__ int hist[NBK];
    __shared__ int cur[NBK];
    const int t = threadIdx.x;
    const int f = detect_i64(ei);
    for (int j = t; j < NBK; j += 1024) hist[j] = 0;
    __syncthreads();
    const int e0 = blockIdx.x * PCHUNK;
    const int e1 = min(e0 + PCHUNK, N_EDGES);
    int es[4], ed[4];
    int ne = 0;
    #pragma unroll
    for (int q = 0; q < 4; ++q) {
        const int e = e0 + t + 1024 * q;
        if (e < e1) {
            es[ne] = ld_src(ei, f, e);
            ed[ne] = ld_dst(ei, f, e);
            ++ne;
        }
    }
    for (int q = 0; q < ne; ++q) atomicAdd(&hist[ed[q] >> 8], 1);
    __syncthreads();
    for (int j = t; j < NBK; j += 1024)
        cur[j] = j * CAPB + atomicAdd(&gcnt[j], hist[j]);
    __syncthreads();
    for (int q = 0; q < ne; ++q) {
        const int bk = ed[q] >> 8;
        const int pos = atomicAdd(&cur[bk], 1);
        if (pos - bk * CAPB < CAPB) bseg[pos] = make_int2(es[q], ed[q]);
    }
}

// -------- Build pass 2: per-bucket fine scatter into fixed-stride CSR --------
__global__ __launch_bounds__(1024) void k_sub(const int* __restrict__ gcnt,
                                              const int2* __restrict__ bseg,
                                              int* __restrict__ cnt,
                                              int* __restrict__ csr_src)
{
    __shared__ int cur[256];
    const int b = blockIdx.x;
    const int t = threadIdx.x;
    if (t < 256) cur[t] = 0;
    __syncthreads();
    const int count = min(gcnt[b], CAPB);
    const int2* seg = bseg + (size_t)b * CAPB;
    for (int i = t; i < count; i += 1024) {
        const int2 e = seg[i];
        const int slot = atomicAdd(&cur[e.y & 255], 1);
        if (slot < CAP) csr_src[((size_t)e.y << 7) + slot] = e.x;
    }
    __syncthreads();
    if (t < 256) {
        const int n = b * 256 + t;
        if (n < N_NODES) cnt[(size_t)n * CNT_PAD] = min(cur[t], CAP);
    }
}

// ---------------- Kernel 1: h1 = x @ W1 (fp16 out) ; a_src1/a_dst1 fused ----------------
// Register-blocked 2 rows x 4 cols; KTILE=64 for 3 blocks/CU occupancy.
__global__ __launch_bounds__(256) void k1_gemm1(
    const float* __restrict__ x, const float* __restrict__ W1,
    const float* __restrict__ att_src1, const float* __restrict__ att_dst1,
    __half* __restrict__ h1, float* __restrict__ a_src1, float* __restrict__ a_dst1)
{
    __shared__ float w1s[IN_CH * 32];        // full K, [k][col]  (32 KB)
    __shared__ float xs[64 * XS_PITCH];      // K-tile of 64      (17.4 KB)
    __shared__ float attss[32], attds[32];
    const int t = threadIdx.x;
    for (int i = t; i < IN_CH * 32; i += 256) w1s[i] = W1[i];
    if (t < 32) { attss[t] = att_src1[t]; attds[t] = att_dst1[t]; }
    const int row0 = blockIdx.x * 64;
    const int colq = t & 7, c4 = colq * 4;
    const int rp = t >> 3;
    const int r0 = rp * 2, r1 = r0 + 1;
    float4 a0 = make_float4(0.f, 0.f, 0.f, 0.f);
    float4 a1 = make_float4(0.f, 0.f, 0.f, 0.f);
    for (int kb = 0; kb < IN_CH; kb += KTILE) {
        __syncthreads();
        #pragma unroll
        for (int i = 0; i < 4; ++i) {        // 64 rows x 16 float4
            const int idx = t + 256 * i;
            const int r = idx >> 4, p = idx & 15;
            const int row = row0 + r;
            float4 vv = make_float4(0.f, 0.f, 0.f, 0.f);
            if (row < N_NODES)
                vv = *(const float4*)(x + (size_t)row * IN_CH + kb + p * 4);
            *(float4*)(&xs[r * XS_PITCH + p * 4]) = vv;
        }
        __syncthreads();
        #pragma unroll 8
        for (int kt = 0; kt < KTILE; ++kt) {
            const float xv0 = xs[r0 * XS_PITCH + kt];
            const float xv1 = xs[r1 * XS_PITCH + kt];
            const float4 wv = *(const float4*)(&w1s[(kb + kt) * 32 + c4]);
            a0.x += xv0 * wv.x; a0.y += xv0 * wv.y;
            a0.z += xv0 * wv.z; a0.w += xv0 * wv.w;
            a1.x += xv1 * wv.x; a1.y += xv1 * wv.y;
            a1.z += xv1 * wv.z; a1.w += xv1 * wv.w;
        }
    }
    const int row_a = row0 + r0, row_b = row0 + r1;
    if (row_a < N_NODES) {
        uint2 p; p.x = f2h2(a0.x, a0.y); p.y = f2h2(a0.z, a0.w);
        *(uint2*)(h1 + (size_t)row_a * 32 + c4) = p;
    }
    if (row_b < N_NODES) {
        uint2 p; p.x = f2h2(a1.x, a1.y); p.y = f2h2(a1.z, a1.w);
        *(uint2*)(h1 + (size_t)row_b * 32 + c4) = p;
    }
    float sa0 = a0.x * attss[c4] + a0.y * attss[c4 + 1]
              + a0.z * attss[c4 + 2] + a0.w * attss[c4 + 3];
    float sd0 = a0.x * attds[c4] + a0.y * attds[c4 + 1]
              + a0.z * attds[c4 + 2] + a0.w * attds[c4 + 3];
    float sa1 = a1.x * attss[c4] + a1.y * attss[c4 + 1]
              + a1.z * attss[c4 + 2] + a1.w * attss[c4 + 3];
    float sd1 = a1.x * attds[c4] + a1.y * attds[c4 + 1]
              + a1.z * attds[c4 + 2] + a1.w * attds[c4 + 3];
    sa0 += __shfl_xor(sa0, 1); sa0 += __shfl_xor(sa0, 2);
    sd0 += __shfl_xor(sd0, 1); sd0 += __shfl_xor(sd0, 2);
    sa1 += __shfl_xor(sa1, 1); sa1 += __shfl_xor(sa1, 2);
    sd1 += __shfl_xor(sd1, 1); sd1 += __shfl_xor(sd1, 2);
    const int head = colq >> 2;
    if ((colq & 3) == 0) {
        if (row_a < N_NODES) {
            a_src1[row_a * 2 + head] = sa0;
            a_dst1[row_a * 2 + head] = sd0;
        }
        if (row_b < N_NODES) {
            a_src1[row_b * 2 + head] = sa1;
            a_dst1[row_b * 2 + head] = sd1;
        }
    }
}

// -------- Layer-1 aggregation: 4 NODES PER WAVE (validated, round-9 form) --------
__global__ __launch_bounds__(256) void k_agg1f(
    const int* __restrict__ cnt, const int* __restrict__ csr_src,
    const float* __restrict__ a_src1, const float* __restrict__ a_dst1,
    const __half* __restrict__ h1,
    const float* __restrict__ b1, const float* __restrict__ W2,
    const float* __restrict__ att_src2, const float* __restrict__ att_dst2,
    __half* __restrict__ h2, float* __restrict__ a_src2, float* __restrict__ a_dst2)
{
    __shared__ float w2s[32 * 16];
    __shared__ float b1s[32], as2[16], ad2[16];
    __shared__ float act_s[16][33];          // 16 nodes/block; +1 pad vs bank conflict
    const int t = threadIdx.x;
    for (int i = t; i < 512; i += 256) w2s[i] = W2[i];
    if (t < 32) b1s[t] = b1[t];
    if (t < 16) { as2[t] = att_src2[t]; ad2[t] = att_dst2[t]; }

    const int lane = t & 63;
    const int wv = t >> 6;
    const int g = lane >> 4;                 // node group within wave
    const int chp = lane & 15;               // channel pair
    const int head = chp >> 3;
    const int node = blockIdx.x * 16 + wv * 4 + g;   // grid 3125*16 = 50000 exact
    const int active = (node < N_NODES);
    const int len = active ? min(cnt[(size_t)node * CNT_PAD], CAP) : 0;
    const int beg = node << 7;
    const float adh = active ? a_dst1[2 * (size_t)node + head] : 0.f;
    const unsigned int* __restrict__ h1u = (const unsigned int*)h1;
    float accx = 0.f, accy = 0.f, sw = 0.f;
    for (int bi = 0; __any(bi < len); bi += 8) {
        int s[8]; float a[8]; unsigned int hw[8]; float w[8];
        #pragma unroll
        for (int j = 0; j < 8; ++j) {
            int sv = csr_src[beg + bi + j];
            s[j] = (bi + j < len) ? sv : 0;  // clamp garbage before address use
        }
        #pragma unroll
        for (int j = 0; j < 8; ++j) a[j] = a_src1[2 * (size_t)s[j] + head];
        #pragma unroll
        for (int j = 0; j < 8; ++j) hw[j] = h1u[(size_t)s[j] * 16 + chp];
        #pragma unroll
        for (int j = 0; j < 8; ++j)
            w[j] = (bi + j < len) ? __expf(lrelu(a[j] + adh)) : 0.f;
        #pragma unroll
        for (int j = 0; j < 8; ++j) {
            const float2 hf = h2f(hw[j]);
            sw += w[j];
            accx += w[j] * hf.x; accy += w[j] * hf.y;
        }
    }
    const float inv = 1.f / (sw + EPS_F);    // full sum held locally — no shfl
    // ---- fused layer-2 transform (was k4_layer2) ----
    const int nl = wv * 4 + g;
    {
        float ax = accx * inv + b1s[2 * chp];
        float ay = accy * inv + b1s[2 * chp + 1];
        ax = ax > 0.f ? ax : expm1f(ax);
        ay = ay > 0.f ? ay : expm1f(ay);
        act_s[nl][2 * chp] = ax;
        act_s[nl][2 * chp + 1] = ay;
    }
    __syncthreads();            // covers w2s/b1s/as2/ad2 loads + act_s writes
    const int nn = t >> 4;                   // node-local 0..15
    const int j2 = t & 15;
    const int node2 = blockIdx.x * 16 + nn;
    float acc2 = 0.f;
    #pragma unroll
    for (int k = 0; k < 32; ++k) acc2 += act_s[nn][k] * w2s[k * 16 + j2];
    if (node2 < N_NODES) h2[(size_t)node2 * 16 + j2] = __float2half(acc2);
    float sa = acc2 * as2[j2], sd = acc2 * ad2[j2];
    sa += __shfl_xor(sa, 1); sa += __shfl_xor(sa, 2);
    sa += __shfl_xor(sa, 4); sa += __shfl_xor(sa, 8);
    sd += __shfl_xor(sd, 1); sd += __shfl_xor(sd, 2);
    sd += __shfl_xor(sd, 4); sd += __shfl_xor(sd, 8);
    if (j2 == 0 && node2 < N_NODES) { a_src2[node2] = sa; a_dst2[node2] = sd; }
}

// -------- Layer-2 aggregation: 8 NODES PER WAVE (agg1f restructure applied) --------
// lane = 8*group + chp; each 8-lane group walks ALL of its node's edges
// 8-deep predicated. 8 independent load chains/wave; no shfl reductions —
// each lane holds the full weight sum and 2 of the 16 out2 channels.
// Epilogue (fused ex-k_prep): each lane computes 2 u-channels + 2 v-channels
// of its node via the LDS act matrix (identical fp32 math/order as before).
__global__ __launch_bounds__(256) void k_agg2f(
    const int* __restrict__ cnt, const int* __restrict__ csr_src,
    const float* __restrict__ a_src2, const float* __restrict__ a_dst2,
    const __half* __restrict__ h2,
    const float* __restrict__ b2, const float* __restrict__ Wm1,
    const float* __restrict__ bm1,
    __half* __restrict__ u, __half* __restrict__ v)
{
    __shared__ float wa[16 * 16], wb[16 * 16];
    __shared__ float b2s[16], bm1s[16];
    __shared__ float act_s[32][18];          // 32 nodes/block; stride 18 (aligned float2, odd/32 banks)
    const int t = threadIdx.x;
    wa[t] = Wm1[t]; wb[t] = Wm1[256 + t];
    if (t < 16) { b2s[t] = b2[t]; bm1s[t] = bm1[t]; }
    __syncthreads();            // close the init race before b2s use below

    const int lane = t & 63;
    const int wv = t >> 6;
    const int g = lane >> 3;                 // node group within wave (0..7)
    const int chp = lane & 7;                // channel pair (0..7)
    const int node = blockIdx.x * 32 + wv * 8 + g;   // grid 1563*32 = 50016, predicated
    const int active = (node < N_NODES);
    const int len = active ? min(cnt[(size_t)node * CNT_PAD], CAP) : 0;
    const int beg = node << 7;
    const float ad = active ? a_dst2[node] : 0.f;
    const unsigned int* __restrict__ h2u = (const unsigned int*)h2;
    float accx = 0.f, accy = 0.f, sw = 0.f;
    for (int bi = 0; __any(bi < len); bi += 8) {
        int s[8]; float a[8]; unsigned int hw[8]; float w[8];
        #pragma unroll
        for (int j = 0; j < 8; ++j) {
            int sv = csr_src[beg + bi + j];   // within bucket (or benign spill into bseg for inactive tail nodes)
            s[j] = (bi + j < len) ? sv : 0;
        }
        #pragma unroll
        for (int j = 0; j < 8; ++j) a[j] = a_src2[s[j]];
        #pragma unroll
        for (int j = 0; j < 8; ++j) hw[j] = h2u[(size_t)s[j] * 8 + chp];
        #pragma unroll
        for (int j = 0; j < 8; ++j)
            w[j] = (bi + j < len) ? __expf(lrelu(a[j] + ad)) : 0.f;
        #pragma unroll
        for (int j = 0; j < 8; ++j) {
            const float2 hf = h2f(hw[j]);
            sw += w[j];
            accx += w[j] * hf.x; accy += w[j] * hf.y;
        }
    }
    const float inv = 1.f / (sw + EPS_F);    // full sum local — no shfl
    // ---- fused edge-MLP node hoist (was k_prep) ----
    const int nl = wv * 8 + g;
    {
        float2 o;
        o.x = accx * inv + b2s[2 * chp];
        o.y = accy * inv + b2s[2 * chp + 1];
        *(float2*)(&act_s[nl][2 * chp]) = o;
    }
    __syncthreads();            // act_s visible block-wide
    const int c0 = 2 * chp, c1 = c0 + 1;
    float su0 = bm1s[c0], su1 = bm1s[c1], sv0 = 0.f, sv1 = 0.f;
    #pragma unroll
    for (int k = 0; k < 16; ++k) {
        const float a = act_s[nl][k];
        su0 += a * wa[k * 16 + c0];
        su1 += a * wa[k * 16 + c1];
        sv0 += a * wb[k * 16 + c0];
        sv1 += a * wb[k * 16 + c1];
    }
    if (active) {
        *(unsigned int*)(u + (size_t)node * 16 + c0) = f2h2(su0, su1);
        *(unsigned int*)(v + (size_t)node * 16 + c0) = f2h2(sv0, sv1);
    }
}

// ---------------- Kernel 7 lite: per-edge tail of the MLP (fp16 gathers) ----------------
__global__ __launch_bounds__(256) void k7_lite(
    const int* __restrict__ ei,
    const __half* __restrict__ u, const __half* __restrict__ v,
    const float* __restrict__ Wm2, const float* __restrict__ bm2,
    float* __restrict__ out)
{
    __shared__ float wm2s[16];
    __shared__ float bm2s;
    const int t = threadIdx.x;
    const int f = detect_i64(ei);
    if (t < 16) wm2s[t] = Wm2[t];
    if (t == 0) bm2s = bm2[0];
    __syncthreads();
    const int e = blockIdx.x * 256 + t;
    if (e >= N_EDGES) return;
    const int s = ld_src(ei, f, e);
    const int d = ld_dst(ei, f, e);
    const uint4* up = (const uint4*)(u + (size_t)s * 16);
    const uint4* vp = (const uint4*)(v + (size_t)d * 16);
    const uint4 ua = up[0], ub = up[1];
    const uint4 va = vp[0], vb = vp[1];
    float fl = bm2s;
    unsigned int uw[8] = {ua.x, ua.y, ua.z, ua.w, ub.x, ub.y, ub.z, ub.w};
    unsigned int vw[8] = {va.x, va.y, va.z, va.w, vb.x, vb.y, vb.z, vb.w};
    #pragma unroll
    for (int i = 0; i < 8; ++i) {
        const float2 a = h2f(uw[i]);
        const float2 b = h2f(vw[i]);
        fl += fmaxf(a.x + b.x, 0.f) * wm2s[2 * i];
        fl += fmaxf(a.y + b.y, 0.f) * wm2s[2 * i + 1];
    }
    out[e] = fmaxf(fl, 0.f);
}

extern "C" void kernel_launch(void* const* d_in, const int* in_sizes, int n_in,
                              void* d_out, int out_size, void* d_ws, size_t ws_size,
                              hipStream_t stream)
{
    const float* x        = (const float*)d_in[0];
    const int*   ei       = (const int*)d_in[1];
    const float* W1       = (const float*)d_in[2];
    const float* att_src1 = (const float*)d_in[3];
    const float* att_dst1 = (const float*)d_in[4];
    const float* b1       = (const float*)d_in[5];
    const float* W2       = (const float*)d_in[6];
    const float* att_src2 = (const float*)d_in[7];
    const float* att_dst2 = (const float*)d_in[8];
    const float* b2       = (const float*)d_in[9];
    const float* Wm1      = (const float*)d_in[10];
    const float* bm1      = (const float*)d_in[11];
    const float* Wm2      = (const float*)d_in[12];
    const float* bm2      = (const float*)d_in[13];

    float* ws = (float*)d_ws;
    size_t off = 0;
    __half* h1 = (__half*)(ws + off); off += 16 * (size_t)N_NODES;
    float* a_src1 = ws + off; off += 2  * (size_t)N_NODES;
    float* a_dst1 = ws + off; off += 2  * (size_t)N_NODES;
    __half* h2 = (__half*)(ws + off); off += 8 * (size_t)N_NODES;
    float* a_src2 = ws + off; off += 1  * (size_t)N_NODES;
    float* a_dst2 = ws + off; off += 1  * (size_t)N_NODES;
    __half* u = (__half*)(ws + off); off += 8 * (size_t)N_NODES;
    __half* v = (__half*)(ws + off); off += 8 * (size_t)N_NODES;
    int* cnt     = (int*)(ws + off);  off += (size_t)N_NODES * CNT_PAD;
    int* csr_src = (int*)(ws + off);  off += (size_t)N_NODES * CAP;
    int2* bseg   = (int2*)(ws + off); off += (size_t)NBK * CAPB * 2;
    int* gcnt    = (int*)(ws + off);  off += 256;
    // total ~54 MB; workspace >= 256 MB — all regions dedicated, no overlays.

    hipMemsetAsync(gcnt, 0, 256 * sizeof(int), stream);
    k_part<<<(N_EDGES + PCHUNK - 1) / PCHUNK, 1024, 0, stream>>>(ei, gcnt, bseg);
    k_sub<<<NBK, 1024, 0, stream>>>(gcnt, bseg, cnt, csr_src);

    k1_gemm1<<<(N_NODES + 63) / 64, 256, 0, stream>>>(
        x, W1, att_src1, att_dst1, h1, a_src1, a_dst1);
    k_agg1f<<<(N_NODES + 15) / 16, 256, 0, stream>>>(
        cnt, csr_src, a_src1, a_dst1, h1, b1, W2, att_src2, att_dst2,
        h2, a_src2, a_dst2);
    k_agg2f<<<(N_NODES + 31) / 32, 256, 0, stream>>>(
        cnt, csr_src, a_src2, a_dst2, h2, b2, Wm1, bm1, u, v);
    k7_lite<<<(N_EDGES + 255) / 256, 256, 0, stream>>>(
        ei, u, v, Wm2, bm2, (float*)d_out);
}

// Round 13
// 239.804 us; speedup vs baseline: 1.4215x; 1.0278x over previous
//
#include <hip/hip_runtime.h>
#include <hip/hip_bf16.h>
#include <hip/hip_fp16.h>

#define N_NODES 50000
#define N_EDGES 1600000
#define IN_CH 256
#define NEG_SLOPE 0.2f
#define EPS_F 1e-16f
#define CNT_PAD 16      // one 64B line per counter (agg kernels read cnt[n*16])
#define CAP 128         // bucket capacity per node (Poisson(32): P(>=128) ~ 1e-37)
#define NBK 196         // coarse buckets: dst>>8, 50000/256 -> 0..195
#define CAPB 10240      // coarse bucket capacity (mean 8163, +23 sigma)
#define PCHUNK 3125     // edges per k_part block (1024 threads x <=4 edges)
#define KTILE 64                 // 17.4KB xs + 32KB w1s -> 3 blocks/CU
#define XS_PITCH (KTILE + 4)

__device__ __forceinline__ float lrelu(float x) {
    return x > 0.f ? x : NEG_SLOPE * x;
}

__device__ __forceinline__ float2 h2f(unsigned int w) {
    __half2 h;
    *reinterpret_cast<unsigned int*>(&h) = w;
    return __half22float2(h);
}

__device__ __forceinline__ unsigned int f2h2(float a, float b) {
    __half2 h = __floats2half2_rn(a, b);
    return *reinterpret_cast<unsigned int*>(&h);
}

// Inline int64-vs-int32 layout detection: for int64 edge_index the high words
// (odd int positions) are all zero (values in [0, 50000)); for int32 they are
// src values, all-zero with P ~ (2e-5)^64. One L2-hot load + ballot per wave.
__device__ __forceinline__ int detect_i64(const int* __restrict__ ei) {
    const int lane = threadIdx.x & 63;
    const unsigned long long b = __ballot(ei[2 * lane + 1] != 0);
    return b == 0ull ? 1 : 0;
}

__device__ __forceinline__ int ld_src(const int* ei, int f, int e) {
    return f ? ei[2 * (size_t)e] : ei[e];
}
__device__ __forceinline__ int ld_dst(const int* ei, int f, int e) {
    return f ? ei[2 * (size_t)N_EDGES + 2 * (size_t)e]
             : ei[(size_t)N_EDGES + e];
}

// -------- Build pass 1: coarse partition by dst>>8, edges register-cached --------
__global__ __launch_bounds__(1024) void k_part(const int* __restrict__ ei,
                                               int* __restrict__ gcnt,
                                               int2* __restrict__ bseg)
{
    __shared__ int hist[NBK];
    __shared__ int cur[NBK];
    const int t = threadIdx.x;
    const int f = detect_i64(ei);
    for (int j = t; j < NBK; j += 1024) hist[j] = 0;
    __syncthreads();
    const int e0 = blockIdx.x * PCHUNK;
    const int e1 = min(e0 + PCHUNK, N_EDGES);
    int es[4], ed[4];
    int ne = 0;
    #pragma unroll
    for (int q = 0; q < 4; ++q) {
        const int e = e0 + t + 1024 * q;
        if (e < e1) {
            es[ne] = ld_src(ei, f, e);
            ed[ne] = ld_dst(ei, f, e);
            ++ne;
        }
    }
    for (int q = 0; q < ne; ++q) atomicAdd(&hist[ed[q] >> 8], 1);
    __syncthreads();
    for (int j = t; j < NBK; j += 1024)
        cur[j] = j * CAPB + atomicAdd(&gcnt[j], hist[j]);
    __syncthreads();
    for (int q = 0; q < ne; ++q) {
        const int bk = ed[q] >> 8;
        const int pos = atomicAdd(&cur[bk], 1);
        if (pos - bk * CAPB < CAPB) bseg[pos] = make_int2(es[q], ed[q]);
    }
}

// -------- Build pass 2: per-bucket fine scatter into fixed-stride CSR --------
__global__ __launch_bounds__(1024) void k_sub(const int* __restrict__ gcnt,
                                              const int2* __restrict__ bseg,
                                              int* __restrict__ cnt,
                                              int* __restrict__ csr_src)
{
    __shared__ int cur[256];
    const int b = blockIdx.x;
    const int t = threadIdx.x;
    if (t < 256) cur[t] = 0;
    __syncthreads();
    const int count = min(gcnt[b], CAPB);
    const int2* seg = bseg + (size_t)b * CAPB;
    for (int i = t; i < count; i += 1024) {
        const int2 e = seg[i];
        const int slot = atomicAdd(&cur[e.y & 255], 1);
        if (slot < CAP) csr_src[((size_t)e.y << 7) + slot] = e.x;
    }
    __syncthreads();
    if (t < 256) {
        const int n = b * 256 + t;
        if (n < N_NODES) cnt[(size_t)n * CNT_PAD] = min(cur[t], CAP);
    }
}

// ---------------- Kernel 1: h1 = x @ W1 (fp16 out) ; a_src1/a_dst1 fused ----------------
// Register-blocked 2 rows x 4 cols; KTILE=64 for 3 blocks/CU occupancy.
__global__ __launch_bounds__(256) void k1_gemm1(
    const float* __restrict__ x, const float* __restrict__ W1,
    const float* __restrict__ att_src1, const float* __restrict__ att_dst1,
    __half* __restrict__ h1, float* __restrict__ a_src1, float* __restrict__ a_dst1)
{
    __shared__ float w1s[IN_CH * 32];        // full K, [k][col]  (32 KB)
    __shared__ float xs[64 * XS_PITCH];      // K-tile of 64      (17.4 KB)
    __shared__ float attss[32], attds[32];
    const int t = threadIdx.x;
    for (int i = t; i < IN_CH * 32; i += 256) w1s[i] = W1[i];
    if (t < 32) { attss[t] = att_src1[t]; attds[t] = att_dst1[t]; }
    const int row0 = blockIdx.x * 64;
    const int colq = t & 7, c4 = colq * 4;
    const int rp = t >> 3;
    const int r0 = rp * 2, r1 = r0 + 1;
    float4 a0 = make_float4(0.f, 0.f, 0.f, 0.f);
    float4 a1 = make_float4(0.f, 0.f, 0.f, 0.f);
    for (int kb = 0; kb < IN_CH; kb += KTILE) {
        __syncthreads();
        #pragma unroll
        for (int i = 0; i < 4; ++i) {        // 64 rows x 16 float4
            const int idx = t + 256 * i;
            const int r = idx >> 4, p = idx & 15;
            const int row = row0 + r;
            float4 vv = make_float4(0.f, 0.f, 0.f, 0.f);
            if (row < N_NODES)
                vv = *(const float4*)(x + (size_t)row * IN_CH + kb + p * 4);
            *(float4*)(&xs[r * XS_PITCH + p * 4]) = vv;
        }
        __syncthreads();
        #pragma unroll 8
        for (int kt = 0; kt < KTILE; ++kt) {
            const float xv0 = xs[r0 * XS_PITCH + kt];
            const float xv1 = xs[r1 * XS_PITCH + kt];
            const float4 wv = *(const float4*)(&w1s[(kb + kt) * 32 + c4]);
            a0.x += xv0 * wv.x; a0.y += xv0 * wv.y;
            a0.z += xv0 * wv.z; a0.w += xv0 * wv.w;
            a1.x += xv1 * wv.x; a1.y += xv1 * wv.y;
            a1.z += xv1 * wv.z; a1.w += xv1 * wv.w;
        }
    }
    const int row_a = row0 + r0, row_b = row0 + r1;
    if (row_a < N_NODES) {
        uint2 p; p.x = f2h2(a0.x, a0.y); p.y = f2h2(a0.z, a0.w);
        *(uint2*)(h1 + (size_t)row_a * 32 + c4) = p;
    }
    if (row_b < N_NODES) {
        uint2 p; p.x = f2h2(a1.x, a1.y); p.y = f2h2(a1.z, a1.w);
        *(uint2*)(h1 + (size_t)row_b * 32 + c4) = p;
    }
    float sa0 = a0.x * attss[c4] + a0.y * attss[c4 + 1]
              + a0.z * attss[c4 + 2] + a0.w * attss[c4 + 3];
    float sd0 = a0.x * attds[c4] + a0.y * attds[c4 + 1]
              + a0.z * attds[c4 + 2] + a0.w * attds[c4 + 3];
    float sa1 = a1.x * attss[c4] + a1.y * attss[c4 + 1]
              + a1.z * attss[c4 + 2] + a1.w * attss[c4 + 3];
    float sd1 = a1.x * attds[c4] + a1.y * attds[c4 + 1]
              + a1.z * attds[c4 + 2] + a1.w * attds[c4 + 3];
    sa0 += __shfl_xor(sa0, 1); sa0 += __shfl_xor(sa0, 2);
    sd0 += __shfl_xor(sd0, 1); sd0 += __shfl_xor(sd0, 2);
    sa1 += __shfl_xor(sa1, 1); sa1 += __shfl_xor(sa1, 2);
    sd1 += __shfl_xor(sd1, 1); sd1 += __shfl_xor(sd1, 2);
    const int head = colq >> 2;
    if ((colq & 3) == 0) {
        if (row_a < N_NODES) {
            a_src1[row_a * 2 + head] = sa0;
            a_dst1[row_a * 2 + head] = sd0;
        }
        if (row_b < N_NODES) {
            a_src1[row_b * 2 + head] = sa1;
            a_dst1[row_b * 2 + head] = sd1;
        }
    }
}

// -------- Layer-1 aggregation: 4 nodes/wave, 16-DEEP batches --------
// Validated round-9 structure; batch depth 8->16 halves the number of
// dependent-chain stalls per node (median degree 32: 4 iters -> 2) and
// doubles loads-in-flight per wave. Dummy tail loads clamp to s=0 (broadcast).
__global__ __launch_bounds__(256) void k_agg1f(
    const int* __restrict__ cnt, const int* __restrict__ csr_src,
    const float* __restrict__ a_src1, const float* __restrict__ a_dst1,
    const __half* __restrict__ h1,
    const float* __restrict__ b1, const float* __restrict__ W2,
    const float* __restrict__ att_src2, const float* __restrict__ att_dst2,
    __half* __restrict__ h2, float* __restrict__ a_src2, float* __restrict__ a_dst2)
{
    __shared__ float w2s[32 * 16];
    __shared__ float b1s[32], as2[16], ad2[16];
    __shared__ float act_s[16][33];          // 16 nodes/block; +1 pad vs bank conflict
    const int t = threadIdx.x;
    for (int i = t; i < 512; i += 256) w2s[i] = W2[i];
    if (t < 32) b1s[t] = b1[t];
    if (t < 16) { as2[t] = att_src2[t]; ad2[t] = att_dst2[t]; }

    const int lane = t & 63;
    const int wv = t >> 6;
    const int g = lane >> 4;                 // node group within wave
    const int chp = lane & 15;               // channel pair
    const int head = chp >> 3;
    const int node = blockIdx.x * 16 + wv * 4 + g;   // grid 3125*16 = 50000 exact
    const int active = (node < N_NODES);
    const int len = active ? min(cnt[(size_t)node * CNT_PAD], CAP) : 0;
    const int beg = node << 7;
    const float adh = active ? a_dst1[2 * (size_t)node + head] : 0.f;
    const unsigned int* __restrict__ h1u = (const unsigned int*)h1;
    float accx = 0.f, accy = 0.f, sw = 0.f;
    for (int bi = 0; __any(bi < len); bi += 16) {
        int s[16]; float a[16]; unsigned int hw[16]; float w[16];
        #pragma unroll
        for (int j = 0; j < 16; ++j) {
            int sv = csr_src[beg + bi + j];  // bi+j <= 127: within own bucket
            s[j] = (bi + j < len) ? sv : 0;  // clamp garbage before address use
        }
        #pragma unroll
        for (int j = 0; j < 16; ++j) a[j] = a_src1[2 * (size_t)s[j] + head];
        #pragma unroll
        for (int j = 0; j < 16; ++j) hw[j] = h1u[(size_t)s[j] * 16 + chp];
        #pragma unroll
        for (int j = 0; j < 16; ++j)
            w[j] = (bi + j < len) ? __expf(lrelu(a[j] + adh)) : 0.f;
        #pragma unroll
        for (int j = 0; j < 16; ++j) {
            const float2 hf = h2f(hw[j]);
            sw += w[j];
            accx += w[j] * hf.x; accy += w[j] * hf.y;
        }
    }
    const float inv = 1.f / (sw + EPS_F);    // full sum held locally — no shfl
    // ---- fused layer-2 transform (was k4_layer2) ----
    const int nl = wv * 4 + g;
    {
        float ax = accx * inv + b1s[2 * chp];
        float ay = accy * inv + b1s[2 * chp + 1];
        ax = ax > 0.f ? ax : expm1f(ax);
        ay = ay > 0.f ? ay : expm1f(ay);
        act_s[nl][2 * chp] = ax;
        act_s[nl][2 * chp + 1] = ay;
    }
    __syncthreads();            // covers w2s/b1s/as2/ad2 loads + act_s writes
    const int nn = t >> 4;                   // node-local 0..15
    const int j2 = t & 15;
    const int node2 = blockIdx.x * 16 + nn;
    float acc2 = 0.f;
    #pragma unroll
    for (int k = 0; k < 32; ++k) acc2 += act_s[nn][k] * w2s[k * 16 + j2];
    if (node2 < N_NODES) h2[(size_t)node2 * 16 + j2] = __float2half(acc2);
    float sa = acc2 * as2[j2], sd = acc2 * ad2[j2];
    sa += __shfl_xor(sa, 1); sa += __shfl_xor(sa, 2);
    sa += __shfl_xor(sa, 4); sa += __shfl_xor(sa, 8);
    sd += __shfl_xor(sd, 1); sd += __shfl_xor(sd, 2);
    sd += __shfl_xor(sd, 4); sd += __shfl_xor(sd, 8);
    if (j2 == 0 && node2 < N_NODES) { a_src2[node2] = sa; a_dst2[node2] = sd; }
}

// -------- Layer-2 aggregation: 8 nodes/wave, 16-DEEP batches --------
__global__ __launch_bounds__(256) void k_agg2f(
    const int* __restrict__ cnt, const int* __restrict__ csr_src,
    const float* __restrict__ a_src2, const float* __restrict__ a_dst2,
    const __half* __restrict__ h2,
    const float* __restrict__ b2, const float* __restrict__ Wm1,
    const float* __restrict__ bm1,
    __half* __restrict__ u, __half* __restrict__ v)
{
    __shared__ float wa[16 * 16], wb[16 * 16];
    __shared__ float b2s[16], bm1s[16];
    __shared__ float act_s[32][18];          // 32 nodes/block; stride 18 (aligned float2, odd/32 banks)
    const int t = threadIdx.x;
    wa[t] = Wm1[t]; wb[t] = Wm1[256 + t];
    if (t < 16) { b2s[t] = b2[t]; bm1s[t] = bm1[t]; }
    __syncthreads();            // close the init race before b2s use below

    const int lane = t & 63;
    const int wv = t >> 6;
    const int g = lane >> 3;                 // node group within wave (0..7)
    const int chp = lane & 7;                // channel pair (0..7)
    const int node = blockIdx.x * 32 + wv * 8 + g;   // grid 1563*32 = 50016, predicated
    const int active = (node < N_NODES);
    const int len = active ? min(cnt[(size_t)node * CNT_PAD], CAP) : 0;
    const int beg = node << 7;
    const float ad = active ? a_dst2[node] : 0.f;
    const unsigned int* __restrict__ h2u = (const unsigned int*)h2;
    float accx = 0.f, accy = 0.f, sw = 0.f;
    for (int bi = 0; __any(bi < len); bi += 16) {
        int s[16]; float a[16]; unsigned int hw[16]; float w[16];
        #pragma unroll
        for (int j = 0; j < 16; ++j) {
            int sv = csr_src[beg + bi + j];   // within bucket (or benign spill for inactive tail nodes)
            s[j] = (bi + j < len) ? sv : 0;
        }
        #pragma unroll
        for (int j = 0; j < 16; ++j) a[j] = a_src2[s[j]];
        #pragma unroll
        for (int j = 0; j < 16; ++j) hw[j] = h2u[(size_t)s[j] * 8 + chp];
        #pragma unroll
        for (int j = 0; j < 16; ++j)
            w[j] = (bi + j < len) ? __expf(lrelu(a[j] + ad)) : 0.f;
        #pragma unroll
        for (int j = 0; j < 16; ++j) {
            const float2 hf = h2f(hw[j]);
            sw += w[j];
            accx += w[j] * hf.x; accy += w[j] * hf.y;
        }
    }
    const float inv = 1.f / (sw + EPS_F);    // full sum local — no shfl
    // ---- fused edge-MLP node hoist (was k_prep) ----
    const int nl = wv * 8 + g;
    {
        float2 o;
        o.x = accx * inv + b2s[2 * chp];
        o.y = accy * inv + b2s[2 * chp + 1];
        *(float2*)(&act_s[nl][2 * chp]) = o;
    }
    __syncthreads();            // act_s visible block-wide
    const int c0 = 2 * chp, c1 = c0 + 1;
    float su0 = bm1s[c0], su1 = bm1s[c1], sv0 = 0.f, sv1 = 0.f;
    #pragma unroll
    for (int k = 0; k < 16; ++k) {
        const float a = act_s[nl][k];
        su0 += a * wa[k * 16 + c0];
        su1 += a * wa[k * 16 + c1];
        sv0 += a * wb[k * 16 + c0];
        sv1 += a * wb[k * 16 + c1];
    }
    if (active) {
        *(unsigned int*)(u + (size_t)node * 16 + c0) = f2h2(su0, su1);
        *(unsigned int*)(v + (size_t)node * 16 + c0) = f2h2(sv0, sv1);
    }
}

// ---------------- Kernel 7 lite: per-edge tail of the MLP (fp16 gathers) ----------------
__global__ __launch_bounds__(256) void k7_lite(
    const int* __restrict__ ei,
    const __half* __restrict__ u, const __half* __restrict__ v,
    const float* __restrict__ Wm2, const float* __restrict__ bm2,
    float* __restrict__ out)
{
    __shared__ float wm2s[16];
    __shared__ float bm2s;
    const int t = threadIdx.x;
    const int f = detect_i64(ei);
    if (t < 16) wm2s[t] = Wm2[t];
    if (t == 0) bm2s = bm2[0];
    __syncthreads();
    const int e = blockIdx.x * 256 + t;
    if (e >= N_EDGES) return;
    const int s = ld_src(ei, f, e);
    const int d = ld_dst(ei, f, e);
    const uint4* up = (const uint4*)(u + (size_t)s * 16);
    const uint4* vp = (const uint4*)(v + (size_t)d * 16);
    const uint4 ua = up[0], ub = up[1];
    const uint4 va = vp[0], vb = vp[1];
    float fl = bm2s;
    unsigned int uw[8] = {ua.x, ua.y, ua.z, ua.w, ub.x, ub.y, ub.z, ub.w};
    unsigned int vw[8] = {va.x, va.y, va.z, va.w, vb.x, vb.y, vb.z, vb.w};
    #pragma unroll
    for (int i = 0; i < 8; ++i) {
        const float2 a = h2f(uw[i]);
        const float2 b = h2f(vw[i]);
        fl += fmaxf(a.x + b.x, 0.f) * wm2s[2 * i];
        fl += fmaxf(a.y + b.y, 0.f) * wm2s[2 * i + 1];
    }
    out[e] = fmaxf(fl, 0.f);
}

extern "C" void kernel_launch(void* const* d_in, const int* in_sizes, int n_in,
                              void* d_out, int out_size, void* d_ws, size_t ws_size,
                              hipStream_t stream)
{
    const float* x        = (const float*)d_in[0];
    const int*   ei       = (const int*)d_in[1];
    const float* W1       = (const float*)d_in[2];
    const float* att_src1 = (const float*)d_in[3];
    const float* att_dst1 = (const float*)d_in[4];
    const float* b1       = (const float*)d_in[5];
    const float* W2       = (const float*)d_in[6];
    const float* att_src2 = (const float*)d_in[7];
    const float* att_dst2 = (const float*)d_in[8];
    const float* b2       = (const float*)d_in[9];
    const float* Wm1      = (const float*)d_in[10];
    const float* bm1      = (const float*)d_in[11];
    const float* Wm2      = (const float*)d_in[12];
    const float* bm2      = (const float*)d_in[13];

    float* ws = (float*)d_ws;
    size_t off = 0;
    __half* h1 = (__half*)(ws + off); off += 16 * (size_t)N_NODES;
    float* a_src1 = ws + off; off += 2  * (size_t)N_NODES;
    float* a_dst1 = ws + off; off += 2  * (size_t)N_NODES;
    __half* h2 = (__half*)(ws + off); off += 8 * (size_t)N_NODES;
    float* a_src2 = ws + off; off += 1  * (size_t)N_NODES;
    float* a_dst2 = ws + off; off += 1  * (size_t)N_NODES;
    __half* u = (__half*)(ws + off); off += 8 * (size_t)N_NODES;
    __half* v = (__half*)(ws + off); off += 8 * (size_t)N_NODES;
    int* cnt     = (int*)(ws + off);  off += (size_t)N_NODES * CNT_PAD;
    int* csr_src = (int*)(ws + off);  off += (size_t)N_NODES * CAP;
    int2* bseg   = (int2*)(ws + off); off += (size_t)NBK * CAPB * 2;
    int* gcnt    = (int*)(ws + off);  off += 256;
    // total ~54 MB; workspace >= 256 MB — all regions dedicated, no overlays.

    hipMemsetAsync(gcnt, 0, 256 * sizeof(int), stream);
    k_part<<<(N_EDGES + PCHUNK - 1) / PCHUNK, 1024, 0, stream>>>(ei, gcnt, bseg);
    k_sub<<<NBK, 1024, 0, stream>>>(gcnt, bseg, cnt, csr_src);

    k1_gemm1<<<(N_NODES + 63) / 64, 256, 0, stream>>>(
        x, W1, att_src1, att_dst1, h1, a_src1, a_dst1);
    k_agg1f<<<(N_NODES + 15) / 16, 256, 0, stream>>>(
        cnt, csr_src, a_src1, a_dst1, h1, b1, W2, att_src2, att_dst2,
        h2, a_src2, a_dst2);
    k_agg2f<<<(N_NODES + 31) / 32, 256, 0, stream>>>(
        cnt, csr_src, a_src2, a_dst2, h2, b2, Wm1, bm1, u, v);
    k7_lite<<<(N_EDGES + 255) / 256, 256, 0, stream>>>(
        ei, u, v, Wm2, bm2, (float*)d_out);
}